// Round 5
// baseline (338.421 us; speedup 1.0000x reference)
//
#include <hip/hip_runtime.h>
#include <hip/hip_bf16.h>

#define T_ 4
#define B_ 4
#define N_ 16384
#define KALL_ 4
#define F_ 16384
#define ORD_ 3
#define DIN_ 4
#define H_ 64
#define H3_ 192
#define DE_ 4
#define STR 72   // padded bf16 leading-dim for MFMA A/B LDS tiles (k_head)
#define NE_ 49152  // F*ORD edges

typedef __attribute__((ext_vector_type(8))) short s16x8;
typedef __attribute__((ext_vector_type(4))) float f32x4;
typedef __attribute__((ext_vector_type(2))) float f32x2;
typedef unsigned long long u64;

static __device__ __forceinline__ float b2f(unsigned short u) {
  union { unsigned u; float f; } x; x.u = ((unsigned)u) << 16; return x.f;
}
static __device__ __forceinline__ unsigned short f2b(float f) {
  __hip_bfloat16 h = __float2bfloat16(f);  // RNE
  union { __hip_bfloat16 h; unsigned short u; } x; x.h = h; return x.u;
}
static __device__ __forceinline__ float sigm_fast(float v) {
  return __builtin_amdgcn_rcpf(1.f + __expf(-v));
}
static __device__ __forceinline__ float tanh_fast(float v) {
  float e = __expf(2.f * v);
  return 1.f - 2.f * __builtin_amdgcn_rcpf(e + 1.f);
}

// ---------------------------------------------------------------------------
// CSR build: inverse of indices[F,ORD] -> per-node edge lists. 49152 entries.
// ---------------------------------------------------------------------------
__global__ __launch_bounds__(256) void k_csr_count(
    const int* __restrict__ idx, int* __restrict__ cnt) {
  int e = blockIdx.x * 256 + threadIdx.x;
  if (e < NE_) atomicAdd(&cnt[idx[e]], 1);
}
__global__ __launch_bounds__(256) void k_csr_scan(
    const int* __restrict__ cnt, int* __restrict__ offs, int* __restrict__ cursor) {
  __shared__ int part[256];
  __shared__ int base[256];
  int t = threadIdx.x;
  int s = 0;
  for (int j = 0; j < 64; ++j) s += cnt[t * 64 + j];
  part[t] = s;
  __syncthreads();
  if (t == 0) {
    int run = 0;
    for (int i = 0; i < 256; ++i) { base[i] = run; run += part[i]; }
  }
  __syncthreads();
  int run = base[t];
  for (int j = 0; j < 64; ++j) {
    offs[t * 64 + j] = run;
    cursor[t * 64 + j] = run;
    run += cnt[t * 64 + j];
  }
  if (t == 255) offs[N_] = run;
}
__global__ __launch_bounds__(256) void k_csr_fill(
    const int* __restrict__ idx, int* __restrict__ cursor, int* __restrict__ elist) {
  int e = blockIdx.x * 256 + threadIdx.x;
  if (e < NE_) {
    int pos = atomicAdd(&cursor[idx[e]], 1);
    elist[pos] = e;
  }
}

// ---------------------------------------------------------------------------
// Prep: Wh -> bf16, transposed + column-permuted so that MFMA D tile ct
// (ct = g*4+cg), lane c15 yields h-index g*64 + 4*c15 + cg. Layout
// whTg[rr*64 + k], rr = 16*ct + c  holds  Wh[k][g*64 + 4*c + cg].
// ---------------------------------------------------------------------------
__global__ __launch_bounds__(256) void k_prep_wh(
    const float* __restrict__ Wh, unsigned short* __restrict__ whTg) {
  int i = blockIdx.x * 256 + threadIdx.x;   // 48*256 = 12288
  int rr = i >> 6, k = i & 63;
  int ct = rr >> 4, c = rr & 15;
  int g = ct >> 2, cg = ct & 3;
  whTg[i] = f2b(Wh[k * H3_ + g * 64 + 4 * c + cg]);
}

// ---------------------------------------------------------------------------
// Prep: Wq/Wk/Wv/Wo -> bf16 transposed wT[m][col][k] so a per-lane MFMA
// B-fragment (8 consecutive k at fixed col) is ONE contiguous 16-B load.
// ---------------------------------------------------------------------------
__global__ __launch_bounds__(256) void k_prep_wa(
    const float* __restrict__ Wq, const float* __restrict__ Wk,
    const float* __restrict__ Wv, const float* __restrict__ Wo,
    unsigned short* __restrict__ wT) {
  int i = blockIdx.x * 256 + threadIdx.x;   // 64*256 = 16384
  int m = i >> 12, col = (i >> 6) & 63, k = i & 63;
  const float* Wm = (m == 0) ? Wq : (m == 1) ? Wk : (m == 2) ? Wv : Wo;
  wT[i] = f2b(Wm[k * 64 + col]);
}

// ---------------------------------------------------------------------------
// Kernel 1: GRU v3. Barrier-free t-loop (carry rows wave-private), carry f32
// in registers, permuted-column WhT. NEW in v3: each t-step is split into two
// cg-halves so only 6 MFMA accumulators (24 VGPR) are live at a time instead
// of 12 (48) -> target total regs <=128 -> 4 waves/SIMD -> all 1024 blocks
// co-resident (R4 counters: VGPR=144 -> 3 waves/SIMD, 2 residency rounds,
// HBM crawling at 1.2 TB/s). Stores happen once per t from cf[].
// ---------------------------------------------------------------------------
__global__ __launch_bounds__(256) void k_gru(
    const float* __restrict__ h0,
    const float* __restrict__ x,
    const int* __restrict__ dones,
    const unsigned short* __restrict__ whTg,
    const float* __restrict__ Wi,
    const float* __restrict__ bi,
    const float* __restrict__ bhn,
    unsigned short* __restrict__ hs,     // [T*B,N,H] bf16
    float* __restrict__ hfin)            // [B,N,H] f32
{
  __shared__ __align__(16) short whT[H3_ * 72];    // 27648 B, bf16 B-tiles
  __shared__ __align__(16) short carry[H_ * 72];   // 9216 B, bf16 A-tiles
  __shared__ float wiS[5 * H3_];                   // 3840 B: Wi rows 0..3, bi row 4

  const int tid = threadIdx.x;
  const int lane = tid & 63;
  const int w = tid >> 6;
  const int c15 = lane & 15;
  const int hi4 = lane >> 4;
  const int bid = blockIdx.x;
  const int b = bid >> 8;
  const int nbase = (bid & 255) * 64;
  const int hb = 4 * c15;                 // contiguous h-base of this lane

  // stage whT (pre-converted, permuted): 6 x 16-byte copies per thread
#pragma unroll
  for (int c = 0; c < 6; ++c) {
    int lin = (c * 256 + tid) * 8;        // element index, 8 bf16 per copy
    int row = lin >> 6, col = lin & 63;
    *(s16x8*)&whT[row * 72 + col] = *(const s16x8*)&whTg[lin];
  }
  // stage Wi (f32) + bias row
  for (int i = tid; i < 5 * H3_; i += 256)
    wiS[i] = (i < 4 * H3_) ? Wi[i] : bi[i - 4 * H3_];

  // carry state in registers + bf16 LDS copy (wave-private rows)
  f32x4 cf[4];
#pragma unroll
  for (int r = 0; r < 4; ++r) {
    int row = 16 * w + 4 * hi4 + r;
    cf[r] = *(const f32x4*)&h0[(size_t)(b * N_ + nbase + row) * H_ + hb];
    u64 pk = 0;
#pragma unroll
    for (int e = 0; e < 4; ++e) pk |= (u64)f2b(cf[r][e]) << (16 * e);
    *(u64*)&carry[row * 72 + hb] = pk;
  }

  float bhnr[4];
#pragma unroll
  for (int cg = 0; cg < 4; ++cg) bhnr[cg] = bhn[hb + cg];

  // hoisted dones decode -> bitmask (no runtime-indexed array: rule #20)
  unsigned dmask = 0;
  {
    bool word = true;
#pragma unroll
    for (int i = 0; i < 16; ++i) {
      int v = dones[i];
      if (v != 0 && v != 1 && v != 0x3F800000) word = false;
    }
#pragma unroll
    for (int t = 0; t < T_; ++t) {
      int tb = t * B_ + b;
      bool d = word ? (dones[tb] != 0) : (((const unsigned char*)dones)[tb] != 0);
      if (d) dmask |= (1u << t);
    }
  }

  __syncthreads();   // whT/wiS visible; after this the t-loop is barrier-free

  const int rowA = 16 * w + c15;
  for (int t = 0; t < T_; ++t) {
    if ((dmask >> t) & 1u) {
#pragma unroll
      for (int r = 0; r < 4; ++r) {
        cf[r] = (f32x4){0.f, 0.f, 0.f, 0.f};
        *(u64*)&carry[(16 * w + 4 * hi4 + r) * 72 + hb] = 0ull;
      }
    }

    // A-fragments for this t (carry rows are wave-private; DS ops in-order)
    s16x8 af0 = *(const s16x8*)&carry[rowA * 72 + hi4 * 8];
    s16x8 af1 = *(const s16x8*)&carry[rowA * 72 + 32 + hi4 * 8];

    // x for all 4 rows, loaded early (independent HBM loads)
    f32x4 xv[4];
#pragma unroll
    for (int r = 0; r < 4; ++r) {
      const int node = nbase + 16 * w + 4 * hi4 + r;
      xv[r] = *(const f32x4*)&x[(size_t)((t * B_ + b) * N_ + node) * DIN_];
    }

    // two cg-halves: hh covers output columns hb+2*hh .. hb+2*hh+1
#pragma unroll
    for (int hh = 0; hh < 2; ++hh) {
      f32x4 acc[6];                       // [g*2+c2], only 24 VGPR live
#pragma unroll
      for (int j = 0; j < 6; ++j) acc[j] = (f32x4){0.f, 0.f, 0.f, 0.f};
#pragma unroll
      for (int j = 0; j < 6; ++j) {
        const int ct = (j >> 1) * 4 + 2 * hh + (j & 1);
        acc[j] = __builtin_amdgcn_mfma_f32_16x16x32_bf16(
            af0, *(const s16x8*)&whT[(16 * ct + c15) * 72 + hi4 * 8], acc[j], 0, 0, 0);
      }
#pragma unroll
      for (int j = 0; j < 6; ++j) {
        const int ct = (j >> 1) * 4 + 2 * hh + (j & 1);
        acc[j] = __builtin_amdgcn_mfma_f32_16x16x32_bf16(
            af1, *(const s16x8*)&whT[(16 * ct + c15) * 72 + 32 + hi4 * 8], acc[j], 0, 0, 0);
      }
      const int hb2 = hb + 2 * hh;
#pragma unroll
      for (int r = 0; r < 4; ++r) {
        f32x2 gi[3];
#pragma unroll
        for (int g = 0; g < 3; ++g) {
          f32x2 s = *(const f32x2*)&wiS[4 * H3_ + g * 64 + hb2];   // bias
#pragma unroll
          for (int kk = 0; kk < 4; ++kk) {
            f32x2 wv = *(const f32x2*)&wiS[kk * H3_ + g * 64 + hb2];
            s += xv[r][kk] * wv;
          }
          gi[g] = s;
        }
#pragma unroll
        for (int c2 = 0; c2 < 2; ++c2) {
          const int cg = 2 * hh + c2;
          float rg = sigm_fast(gi[0][c2] + acc[c2][r]);
          float zg = sigm_fast(gi[1][c2] + acc[2 + c2][r]);
          float ng = tanh_fast(gi[2][c2] + rg * (acc[4 + c2][r] + bhnr[cg]));
          float nc = zg * (cf[r][cg] - ng) + ng;   // (1-z)n + z*c
          cf[r][cg] = nc;
        }
      }
    }

    // single store phase per t from cf
#pragma unroll
    for (int r = 0; r < 4; ++r) {
      const int row = 16 * w + 4 * hi4 + r;
      const int node = nbase + row;
      u64 pk = 0;
#pragma unroll
      for (int e = 0; e < 4; ++e) pk |= (u64)f2b(cf[r][e]) << (16 * e);
      *(u64*)&hs[(size_t)((t * B_ + b) * N_ + node) * H_ + hb] = pk;
      *(u64*)&carry[row * 72 + hb] = pk;
      if (t == T_ - 1)
        *(f32x4*)&hfin[(size_t)(b * N_ + node) * H_ + hb] = cf[r];
    }
    // no __syncthreads: carry rows are wave-private, whT/wiS read-only
  }
}

// ---------------------------------------------------------------------------
// Kernel 2 v4: ONE (t,b) slice per block (grid 8192 = 8 slices x 1024
// f-chunks). R4 evidence: all kernels latency-bound; the old 8-slice loop
// serialized 32 barriers per block. Weights come from pre-transposed bf16 wT
// (one 16-B load per B-fragment). 4 barriers/block, no atomics; per-edge
// a=o@Wo+bo stored as coalesced bf16 rows. Frag stores XOR-swizzled.
// ---------------------------------------------------------------------------
__global__ __launch_bounds__(256) void k_attn(
    const int tb0,
    const unsigned short* __restrict__ hs,    // [T*B,N,H] bf16
    const int* __restrict__ indices,
    const unsigned short* __restrict__ wT,    // [4][64][64] bf16 (col-major k)
    const float* __restrict__ bq, const float* __restrict__ bk,
    const float* __restrict__ bv, const float* __restrict__ bo,
    unsigned short* __restrict__ a_edge)      // [8,NE,H] bf16
{
  __shared__ __align__(16) unsigned short bufrag[3072]; // A/o frags (swizzled)
  __shared__ __align__(8)  unsigned short qkvs[9792];   // 3 x 48 x 68
  __shared__ float biasf[4][64];
  __shared__ int idxs[48];

  const int tid = threadIdx.x;
  const int lane = tid & 63;
  const int w = tid >> 6;
  const int c15 = lane & 15;
  const int hi4 = lane >> 4;
  const int bid = blockIdx.x;
  const int slice = bid >> 10;                // 0..7
  const int fch = bid & 1023;                 // factor chunk (16 factors)
  const int col = 16 * w + c15;
  const int swz = (c15 ^ (hi4 << 2));         // swizzled frag-read row

  if (tid < 48) idxs[tid] = indices[fch * 48 + tid];
  if (tid < 64) {
    biasf[0][tid] = bq[tid];
    biasf[1][tid] = bk[tid];
    biasf[2][tid] = bv[tid];
    biasf[3][tid] = bo[tid];
  }

  // per-wave B fragments: one contiguous 16-B load each from wT
  s16x8 wB[3][2], wB3[2];
#pragma unroll
  for (int m = 0; m < 3; ++m)
#pragma unroll
    for (int ks = 0; ks < 2; ++ks)
      wB[m][ks] = *(const s16x8*)&wT[(m * 64 + col) * 64 + ks * 32 + hi4 * 8];
#pragma unroll
  for (int ks = 0; ks < 2; ++ks)
    wB3[ks] = *(const s16x8*)&wT[(3 * 64 + col) * 64 + ks * 32 + hi4 * 8];
  __syncthreads();                            // idxs/biasf ready

  // gather: thread covers (row=idx>>4, g=idx&15), u64 each
  const size_t hbase = (size_t)(tb0 + slice) * N_;
  u64 pf[3];
#pragma unroll
  for (int k = 0; k < 3; ++k) {
    int idx = k * 256 + tid, row = idx >> 4, g = idx & 15;
    pf[k] = *(const u64*)&hs[(hbase + idxs[row]) * H_ + g * 4];
  }
#pragma unroll
  for (int k = 0; k < 3; ++k) {               // swizzled frag-layout store
    int idx = k * 256 + tid, row = idx >> 4, g = idx & 15;
    int rt = row >> 4, cr = row & 15;
    int ks = g >> 3, h5 = (g >> 1) & 3, j = (g & 1) * 4;
    int cr2 = cr ^ (h5 << 2);
    *(u64*)&bufrag[((rt * 2 + ks) << 9) + ((h5 * 16 + cr2) << 3) + j] = pf[k];
  }
  __syncthreads();

  // ---- QKV projections (per wave: 3 m x 3 rt tiles at ct=w) ----
  s16x8 afr[3][2];
#pragma unroll
  for (int rt = 0; rt < 3; ++rt)
#pragma unroll
    for (int ks = 0; ks < 2; ++ks)
      afr[rt][ks] = *(const s16x8*)&bufrag[((rt * 2 + ks) << 9) + ((hi4 * 16 + swz) << 3)];
#pragma unroll
  for (int m = 0; m < 3; ++m) {
    float bias = biasf[m][col];
    float scl = (m == 0) ? 0.25f : 1.f;       // 1/sqrt(HD) folded into q
#pragma unroll
    for (int rt = 0; rt < 3; ++rt) {
      f32x4 acc = (f32x4){0.f, 0.f, 0.f, 0.f};
      acc = __builtin_amdgcn_mfma_f32_16x16x32_bf16(afr[rt][0], wB[m][0], acc, 0, 0, 0);
      acc = __builtin_amdgcn_mfma_f32_16x16x32_bf16(afr[rt][1], wB[m][1], acc, 0, 0, 0);
#pragma unroll
      for (int r = 0; r < 4; ++r) {
        int row = 16 * rt + hi4 * 4 + r;
        qkvs[m * 3264 + row * 68 + col] = f2b((acc[r] + bias) * scl);
      }
    }
  }
  __syncthreads();

  // ---- softmax + PV: thread = (f, head, dq); b64 LDS reads ----
  {
    int f = tid >> 4, head = (tid >> 2) & 3, dq = tid & 3;
    int colb = head * 16 + dq * 4;
    float qv[3][4], kv[3][4], vv[3][4];
#pragma unroll
    for (int qi = 0; qi < 3; ++qi) {
      int base = (3 * f + qi) * 68 + colb;
      u64 uq = *(const u64*)&qkvs[base];
      u64 uk = *(const u64*)&qkvs[3264 + base];
      u64 uv = *(const u64*)&qkvs[6528 + base];
#pragma unroll
      for (int e = 0; e < 4; ++e) {
        qv[qi][e] = b2f((unsigned short)(uq >> (16 * e)));
        kv[qi][e] = b2f((unsigned short)(uk >> (16 * e)));
        vv[qi][e] = b2f((unsigned short)(uv >> (16 * e)));
      }
    }
    float s[3][3];
#pragma unroll
    for (int qi = 0; qi < 3; ++qi)
#pragma unroll
      for (int ki = 0; ki < 3; ++ki) {
        float a = qv[qi][0] * kv[ki][0] + qv[qi][1] * kv[ki][1]
                + qv[qi][2] * kv[ki][2] + qv[qi][3] * kv[ki][3];
        a += __shfl_xor(a, 1, 64);
        a += __shfl_xor(a, 2, 64);
        s[qi][ki] = a;
      }
    const int ks2 = colb >> 5, h5b = (colb >> 3) & 3, jb = colb & 7;
#pragma unroll
    for (int qi = 0; qi < 3; ++qi) {
      float mx = fmaxf(s[qi][0], fmaxf(s[qi][1], s[qi][2]));
      float e0 = __expf(s[qi][0] - mx), e1 = __expf(s[qi][1] - mx), e2 = __expf(s[qi][2] - mx);
      float inv = 1.f / (e0 + e1 + e2);
      e0 *= inv; e1 *= inv; e2 *= inv;
      int row = 3 * f + qi;
      int rt = row >> 4, cr2 = (row & 15) ^ (h5b << 2);
      u64 pack = 0;
#pragma unroll
      for (int e = 0; e < 4; ++e) {
        float o = e0 * vv[0][e] + e1 * vv[1][e] + e2 * vv[2][e];
        pack |= (u64)f2b(o) << (16 * e);
      }
      *(u64*)&bufrag[((rt * 2 + ks2) << 9) + ((h5b * 16 + cr2) << 3) + jb] = pack;
    }
  }
  __syncthreads();

  // ---- a = o @ Wo + bo, coalesced bf16 store (NO atomics) ----
  {
    const float bo_ = biasf[3][col];
    const size_t abase = (size_t)slice * NE_ + (size_t)fch * 48;
#pragma unroll
    for (int rt = 0; rt < 3; ++rt) {
      s16x8 o0 = *(const s16x8*)&bufrag[((rt * 2 + 0) << 9) + ((hi4 * 16 + swz) << 3)];
      s16x8 o1 = *(const s16x8*)&bufrag[((rt * 2 + 1) << 9) + ((hi4 * 16 + swz) << 3)];
      f32x4 acc = (f32x4){0.f, 0.f, 0.f, 0.f};
      acc = __builtin_amdgcn_mfma_f32_16x16x32_bf16(o0, wB3[0], acc, 0, 0, 0);
      acc = __builtin_amdgcn_mfma_f32_16x16x32_bf16(o1, wB3[1], acc, 0, 0, 0);
#pragma unroll
      for (int r = 0; r < 4; ++r) {
        int row = 16 * rt + hi4 * 4 + r;
        a_edge[(abase + row) * H_ + col] = f2b(acc[r] + bo_);
      }
    }
  }
}

// ---------------------------------------------------------------------------
// Kernel 3 v2: one half (8 tb). LDS-staged elist + branchless UF=8 predicated
// gather (R4: 54 -> <50 µs, verified). Grid 2048 = 8 ls x 256.
// ---------------------------------------------------------------------------
__global__ __launch_bounds__(256) void k_head(
    const int tb0,
    const unsigned short* __restrict__ a_edge, // [8,NE,H] bf16
    const int* __restrict__ offs, const int* __restrict__ elist,
    const float* __restrict__ nnz,
    const float* __restrict__ extra,
    const float* __restrict__ W1, const float* __restrict__ b1,
    const float* __restrict__ W2, const float* __restrict__ b2,
    float* __restrict__ yg,                    // [T*B,KALL,H] f32, pre-zeroed
    float* __restrict__ logit)                 // [T,B,N] f32
{
  __shared__ short w1T[64 * STR];
  __shared__ short arow[64 * STR];
  __shared__ int offsS[65];
  __shared__ int eidS[512];
  __shared__ float hEx[64];
  __shared__ float w2s[64];
  __shared__ float red[4][64];

  const int tid = threadIdx.x;
  const int lane = tid & 63;
  const int w = tid >> 6;
  const int c15 = lane & 15;
  const int hi4 = lane >> 4;
  const int bid = blockIdx.x;
  const int ls = bid >> 8;             // local slice 0..7
  const int tb = tb0 + ls;
  const int nbase = (bid & 255) * 64;
  const int kall = nbase >> 12;

  for (int i = tid; i < 4096; i += 256) {
    int k = i >> 6, colc = i & 63;
    w1T[colc * STR + k] = (short)f2b(W1[i]);
  }
  if (tid < 65) offsS[tid] = offs[nbase + tid];
  if (tid < 64) {
    float s = b1[tid];
#pragma unroll
    for (int e = 0; e < 4; ++e)
      s += extra[(tb * KALL_ + kall) * DE_ + e] * W1[(64 + e) * 64 + tid];
    hEx[tid] = s;
    w2s[tid] = W2[tid];
  }
  // edge-range staging (every thread loads the two bounds directly: no
  // barrier dependency on offsS)
  const int ebeg = offs[nbase];
  const int ecnt = offs[nbase + 64] - ebeg;
  const bool fast = (ecnt <= 512);
  if (tid == 0) eidS[0] = 0;           // safe dup slot even when ecnt == 0
  if (fast) {
    for (int j = tid; j < ecnt; j += 256) eidS[j] = elist[ebeg + j];
  }
  __syncthreads();

  const size_t ebase = (size_t)ls * NE_;
  float accp = 0.f;
  if (fast) {
    for (int r = w; r < 64; r += 4) {
      const int beg = offsS[r] - ebeg, end = offsS[r + 1] - ebeg;
      float s = 0.f;
#pragma unroll
      for (int u = 0; u < 8; ++u) {
        int p = beg + u;
        bool valid = p < end;
        int pc = valid ? p : 0;        // dup -> eidS[0], L1-hot row
        float v = b2f(a_edge[(ebase + eidS[pc]) * H_ + lane]);
        s += valid ? v : 0.f;
      }
      for (int p = beg + 8; p < end; ++p)          // rare tail (cnt > 8)
        s += b2f(a_edge[(ebase + eidS[p]) * H_ + lane]);
      float val = s / fmaxf((float)(end - beg), 1.f);
      accp += val;
      arow[r * STR + lane] = (short)f2b(val);
    }
  } else {
    // fallback: direct-global dynamic loop (never taken for this input size)
    for (int r = w; r < 64; r += 4) {
      const int beg = offsS[r], end = offsS[r + 1];
      float s = 0.f;
      for (int p = beg; p < end; ++p)
        s += b2f(a_edge[(ebase + elist[p]) * H_ + lane]);
      float val = s / fmaxf((float)(end - beg), 1.f);
      accp += val;
      arow[r * STR + lane] = (short)f2b(val);
    }
  }
  red[w][lane] = accp;
  __syncthreads();

  f32x4 acc[4];
#pragma unroll
  for (int ct = 0; ct < 4; ++ct) acc[ct] = (f32x4){0.f, 0.f, 0.f, 0.f};
#pragma unroll
  for (int ks = 0; ks < 2; ++ks) {
    int kb = ks * 32 + hi4 * 8;
    s16x8 af = *(const s16x8*)&arow[(16 * w + c15) * STR + kb];
#pragma unroll
    for (int ct = 0; ct < 4; ++ct) {
      s16x8 bfr = *(const s16x8*)&w1T[(16 * ct + c15) * STR + kb];
      acc[ct] = __builtin_amdgcn_mfma_f32_16x16x32_bf16(af, bfr, acc[ct], 0, 0, 0);
    }
  }
  const float b2v = b2[0];
#pragma unroll
  for (int r = 0; r < 4; ++r) {
    float s = 0.f;
#pragma unroll
    for (int ct = 0; ct < 4; ++ct) {
      int colc = 16 * ct + c15;
      s += fmaxf(acc[ct][r] + hEx[colc], 0.f) * w2s[colc];
    }
    s += __shfl_xor(s, 1, 64);
    s += __shfl_xor(s, 2, 64);
    s += __shfl_xor(s, 4, 64);
    s += __shfl_xor(s, 8, 64);
    if (c15 == 0)
      logit[tb * N_ + nbase + 16 * w + hi4 * 4 + r] = s + b2v;
  }
  if (tid < 64) {
    float sv = red[0][tid] + red[1][tid] + red[2][tid] + red[3][tid];
    atomicAdd(&yg[(tb * KALL_ + kall) * H_ + tid], sv);
  }
}

// ---------------------------------------------------------------------------
// Kernel 4: value head + h_global passthrough (f32)
// ---------------------------------------------------------------------------
__global__ __launch_bounds__(256) void k_final(
    const float* __restrict__ yg,
    const float* __restrict__ extra,
    const float* __restrict__ Wv1, const float* __restrict__ bv1,
    const float* __restrict__ hg_in,
    float* __restrict__ value_out,
    float* __restrict__ hg_out)
{
  const int tid = threadIdx.x;
  if (tid < 16) {
    const float bv = bv1[0];
    float v = 0.f;
    for (int kall = 0; kall < 4; ++kall) {
      float s = bv;
      for (int hh = 0; hh < 64; ++hh)
        s += (yg[(tid * KALL_ + kall) * H_ + hh] * (1.f / 4096.f)) * Wv1[hh];
      for (int e = 0; e < 4; ++e)
        s += extra[(tid * KALL_ + kall) * DE_ + e] * Wv1[64 + e];
      v += s;
    }
    value_out[tid] = v;
  }
  for (int i = tid; i < 1024; i += 256) hg_out[i] = hg_in[i];
}

// ---------------------------------------------------------------------------
// Workspace layout (84.4 MB, proven safe):
//   yg     @ 0        : 16,384 B    f32 [T*B,KALL,H]
//   cnt    @ 16384    : 65,536 B    int [N]
//   offs   @ 81920    : 65,540 B    int [N+1]
//   cursor @ 147584   : 65,536 B    int [N]
//   elist  @ 213120   : 196,608 B   int [NE]
//   whTg   @ 409728   : 24,576 B    bf16 [192][64] permuted WhT
//   wT     @ 434304   : 32,768 B    bf16 [4][64][64] transposed Wq/Wk/Wv/Wo
//   hs     @ 524288   : 33,554,432 B bf16 [T*B,N,H]
//   a_edge @ 34078720 : 50,331,648 B bf16 [8,NE,H]  (reused per half)
// ---------------------------------------------------------------------------
extern "C" void kernel_launch(void* const* d_in, const int* in_sizes, int n_in,
                              void* d_out, int out_size, void* d_ws, size_t ws_size,
                              hipStream_t stream)
{
  (void)in_sizes; (void)n_in; (void)out_size; (void)ws_size;
  const float* h0    = (const float*)d_in[0];
  const float* hg    = (const float*)d_in[1];
  const float* x     = (const float*)d_in[2];
  const float* extra = (const float*)d_in[3];
  const int*   dn    = (const int*)d_in[4];
  const int*   idx   = (const int*)d_in[5];
  const float* nnz   = (const float*)d_in[6];
  const float* Wi    = (const float*)d_in[7];
  const float* bi    = (const float*)d_in[8];
  const float* Wh    = (const float*)d_in[9];
  const float* bhn   = (const float*)d_in[10];
  const float* Wq    = (const float*)d_in[11];
  const float* bq    = (const float*)d_in[12];
  const float* Wk    = (const float*)d_in[13];
  const float* bk    = (const float*)d_in[14];
  const float* Wv    = (const float*)d_in[15];
  const float* bv    = (const float*)d_in[16];
  const float* Wo    = (const float*)d_in[17];
  const float* bo    = (const float*)d_in[18];
  const float* W1    = (const float*)d_in[19];
  const float* b1    = (const float*)d_in[20];
  const float* W2    = (const float*)d_in[21];
  const float* b2    = (const float*)d_in[22];
  const float* Wv1   = (const float*)d_in[23];
  const float* bv1   = (const float*)d_in[24];

  float* out = (float*)d_out;
  float* out_hfin  = out;                 // [B,N,H]    4194304
  float* out_hg    = out + 4194304;       // [B,K,DOUT]    1024
  float* out_logit = out + 4195328;       // [T,B,N]     262144
  float* out_value = out + 4457472;       // [T,B]           16

  char* wsb = (char*)d_ws;
  float*          yg     = (float*)wsb;
  int*            cnt    = (int*)(wsb + 16384);
  int*            offs   = (int*)(wsb + 81920);
  int*            cursor = (int*)(wsb + 147584);
  int*            elist  = (int*)(wsb + 213120);
  unsigned short* whTg   = (unsigned short*)(wsb + 409728);
  unsigned short* wT     = (unsigned short*)(wsb + 434304);
  unsigned short* hs     = (unsigned short*)(wsb + 524288);
  unsigned short* a_edge = (unsigned short*)(wsb + 34078720);

  hipMemsetAsync(wsb, 0, 81920, stream);      // yg + cnt
  k_csr_count<<<192, 256, 0, stream>>>(idx, cnt);
  k_csr_scan<<<1, 256, 0, stream>>>(cnt, offs, cursor);
  k_csr_fill<<<192, 256, 0, stream>>>(idx, cursor, elist);
  k_prep_wh<<<48, 256, 0, stream>>>(Wh, whTg);
  k_prep_wa<<<64, 256, 0, stream>>>(Wq, Wk, Wv, Wo, wT);
  k_gru<<<1024, 256, 0, stream>>>(h0, x, dn, whTg, Wi, bi, bhn, hs, out_hfin);
  for (int half = 0; half < 2; ++half) {
    const int tb0 = half * 8;
    k_attn<<<8192, 256, 0, stream>>>(tb0, hs, idx, wT, bq, bk, bv, bo, a_edge);
    k_head<<<2048, 256, 0, stream>>>(tb0, a_edge, offs, elist, nnz, extra,
                                     W1, b1, W2, b2, yg, out_logit);
  }
  k_final<<<1, 256, 0, stream>>>(yg, extra, Wv1, bv1, hg, out_value, out_hg);
}

// Round 6
// 334.276 us; speedup vs baseline: 1.0124x; 1.0124x over previous
//
#include <hip/hip_runtime.h>
#include <hip/hip_bf16.h>

#define T_ 4
#define B_ 4
#define N_ 16384
#define KALL_ 4
#define F_ 16384
#define ORD_ 3
#define DIN_ 4
#define H_ 64
#define H3_ 192
#define DE_ 4
#define STR 72   // padded bf16 leading-dim for MFMA A/B LDS tiles (k_head)
#define NE_ 49152  // F*ORD edges

typedef __attribute__((ext_vector_type(8))) short s16x8;
typedef __attribute__((ext_vector_type(4))) float f32x4;
typedef __attribute__((ext_vector_type(2))) float f32x2;
typedef unsigned long long u64;

static __device__ __forceinline__ float b2f(unsigned short u) {
  union { unsigned u; float f; } x; x.u = ((unsigned)u) << 16; return x.f;
}
static __device__ __forceinline__ unsigned short f2b(float f) {
  __hip_bfloat16 h = __float2bfloat16(f);  // RNE
  union { __hip_bfloat16 h; unsigned short u; } x; x.h = h; return x.u;
}
static __device__ __forceinline__ float sigm_fast(float v) {
  return __builtin_amdgcn_rcpf(1.f + __expf(-v));
}
static __device__ __forceinline__ float tanh_fast(float v) {
  float e = __expf(2.f * v);
  return 1.f - 2.f * __builtin_amdgcn_rcpf(e + 1.f);
}

// ---------------------------------------------------------------------------
// Fused prep: CSR count (blocks 0..191) + Wh permute/convert (192..239) +
// attn-weight transpose/convert (240..303). Saves 2 kernel launches.
// ---------------------------------------------------------------------------
__global__ __launch_bounds__(256) void k_prep(
    const int* __restrict__ idx, int* __restrict__ cnt,
    const float* __restrict__ Wh, unsigned short* __restrict__ whTg,
    const float* __restrict__ Wq, const float* __restrict__ Wk,
    const float* __restrict__ Wv, const float* __restrict__ Wo,
    unsigned short* __restrict__ wT) {
  const int b = blockIdx.x, tid = threadIdx.x;
  if (b < 192) {
    int e = b * 256 + tid;
    if (e < NE_) atomicAdd(&cnt[idx[e]], 1);
  } else if (b < 240) {
    // whTg[rr*64+k], rr=16*ct+c, ct=g*4+cg holds Wh[k][g*64+4*c+cg]
    int i = (b - 192) * 256 + tid;        // 48*256 = 12288
    int rr = i >> 6, k = i & 63;
    int ct = rr >> 4, c = rr & 15;
    int g = ct >> 2, cg = ct & 3;
    whTg[i] = f2b(Wh[k * H3_ + g * 64 + 4 * c + cg]);
  } else {
    // wT[m][col][k] so a per-lane B-fragment is one contiguous 16-B load
    int i = (b - 240) * 256 + tid;        // 64*256 = 16384
    int m = i >> 12, col = (i >> 6) & 63, k = i & 63;
    const float* Wm = (m == 0) ? Wq : (m == 1) ? Wk : (m == 2) ? Wv : Wo;
    wT[i] = f2b(Wm[k * 64 + col]);
  }
}

__global__ __launch_bounds__(256) void k_csr_scan(
    const int* __restrict__ cnt, int* __restrict__ offs, int* __restrict__ cursor) {
  __shared__ int part[256];
  __shared__ int base[256];
  int t = threadIdx.x;
  int s = 0;
  for (int j = 0; j < 64; ++j) s += cnt[t * 64 + j];
  part[t] = s;
  __syncthreads();
  if (t == 0) {
    int run = 0;
    for (int i = 0; i < 256; ++i) { base[i] = run; run += part[i]; }
  }
  __syncthreads();
  int run = base[t];
  for (int j = 0; j < 64; ++j) {
    offs[t * 64 + j] = run;
    cursor[t * 64 + j] = run;
    run += cnt[t * 64 + j];
  }
  if (t == 255) offs[N_] = run;
}
__global__ __launch_bounds__(256) void k_csr_fill(
    const int* __restrict__ idx, int* __restrict__ cursor, int* __restrict__ elist) {
  int e = blockIdx.x * 256 + threadIdx.x;
  if (e < NE_) {
    int pos = atomicAdd(&cursor[idx[e]], 1);
    elist[pos] = e;
  }
}

// ---------------------------------------------------------------------------
// Kernel 1: GRU v3 (verified R5). Barrier-free t-loop, carry f32 in regs,
// permuted-column WhT, two cg-halves so only 6 accumulators live at a time.
// ---------------------------------------------------------------------------
__global__ __launch_bounds__(256) void k_gru(
    const float* __restrict__ h0,
    const float* __restrict__ x,
    const int* __restrict__ dones,
    const unsigned short* __restrict__ whTg,
    const float* __restrict__ Wi,
    const float* __restrict__ bi,
    const float* __restrict__ bhn,
    unsigned short* __restrict__ hs,     // [T*B,N,H] bf16
    float* __restrict__ hfin)            // [B,N,H] f32
{
  __shared__ __align__(16) short whT[H3_ * 72];    // 27648 B, bf16 B-tiles
  __shared__ __align__(16) short carry[H_ * 72];   // 9216 B, bf16 A-tiles
  __shared__ float wiS[5 * H3_];                   // 3840 B: Wi rows 0..3, bi row 4

  const int tid = threadIdx.x;
  const int lane = tid & 63;
  const int w = tid >> 6;
  const int c15 = lane & 15;
  const int hi4 = lane >> 4;
  const int bid = blockIdx.x;
  const int b = bid >> 8;
  const int nbase = (bid & 255) * 64;
  const int hb = 4 * c15;                 // contiguous h-base of this lane

  // stage whT (pre-converted, permuted): 6 x 16-byte copies per thread
#pragma unroll
  for (int c = 0; c < 6; ++c) {
    int lin = (c * 256 + tid) * 8;        // element index, 8 bf16 per copy
    int row = lin >> 6, col = lin & 63;
    *(s16x8*)&whT[row * 72 + col] = *(const s16x8*)&whTg[lin];
  }
  // stage Wi (f32) + bias row
  for (int i = tid; i < 5 * H3_; i += 256)
    wiS[i] = (i < 4 * H3_) ? Wi[i] : bi[i - 4 * H3_];

  // carry state in registers + bf16 LDS copy (wave-private rows)
  f32x4 cf[4];
#pragma unroll
  for (int r = 0; r < 4; ++r) {
    int row = 16 * w + 4 * hi4 + r;
    cf[r] = *(const f32x4*)&h0[(size_t)(b * N_ + nbase + row) * H_ + hb];
    u64 pk = 0;
#pragma unroll
    for (int e = 0; e < 4; ++e) pk |= (u64)f2b(cf[r][e]) << (16 * e);
    *(u64*)&carry[row * 72 + hb] = pk;
  }

  float bhnr[4];
#pragma unroll
  for (int cg = 0; cg < 4; ++cg) bhnr[cg] = bhn[hb + cg];

  // hoisted dones decode -> bitmask (no runtime-indexed array: rule #20)
  unsigned dmask = 0;
  {
    bool word = true;
#pragma unroll
    for (int i = 0; i < 16; ++i) {
      int v = dones[i];
      if (v != 0 && v != 1 && v != 0x3F800000) word = false;
    }
#pragma unroll
    for (int t = 0; t < T_; ++t) {
      int tb = t * B_ + b;
      bool d = word ? (dones[tb] != 0) : (((const unsigned char*)dones)[tb] != 0);
      if (d) dmask |= (1u << t);
    }
  }

  __syncthreads();   // whT/wiS visible; after this the t-loop is barrier-free

  const int rowA = 16 * w + c15;
  for (int t = 0; t < T_; ++t) {
    if ((dmask >> t) & 1u) {
#pragma unroll
      for (int r = 0; r < 4; ++r) {
        cf[r] = (f32x4){0.f, 0.f, 0.f, 0.f};
        *(u64*)&carry[(16 * w + 4 * hi4 + r) * 72 + hb] = 0ull;
      }
    }

    // A-fragments for this t (carry rows are wave-private; DS ops in-order)
    s16x8 af0 = *(const s16x8*)&carry[rowA * 72 + hi4 * 8];
    s16x8 af1 = *(const s16x8*)&carry[rowA * 72 + 32 + hi4 * 8];

    // x for all 4 rows, loaded early (independent HBM loads)
    f32x4 xv[4];
#pragma unroll
    for (int r = 0; r < 4; ++r) {
      const int node = nbase + 16 * w + 4 * hi4 + r;
      xv[r] = *(const f32x4*)&x[(size_t)((t * B_ + b) * N_ + node) * DIN_];
    }

    // two cg-halves: hh covers output columns hb+2*hh .. hb+2*hh+1
#pragma unroll
    for (int hh = 0; hh < 2; ++hh) {
      f32x4 acc[6];                       // [g*2+c2], only 24 VGPR live
#pragma unroll
      for (int j = 0; j < 6; ++j) acc[j] = (f32x4){0.f, 0.f, 0.f, 0.f};
#pragma unroll
      for (int j = 0; j < 6; ++j) {
        const int ct = (j >> 1) * 4 + 2 * hh + (j & 1);
        acc[j] = __builtin_amdgcn_mfma_f32_16x16x32_bf16(
            af0, *(const s16x8*)&whT[(16 * ct + c15) * 72 + hi4 * 8], acc[j], 0, 0, 0);
      }
#pragma unroll
      for (int j = 0; j < 6; ++j) {
        const int ct = (j >> 1) * 4 + 2 * hh + (j & 1);
        acc[j] = __builtin_amdgcn_mfma_f32_16x16x32_bf16(
            af1, *(const s16x8*)&whT[(16 * ct + c15) * 72 + 32 + hi4 * 8], acc[j], 0, 0, 0);
      }
      const int hb2 = hb + 2 * hh;
#pragma unroll
      for (int r = 0; r < 4; ++r) {
        f32x2 gi[3];
#pragma unroll
        for (int g = 0; g < 3; ++g) {
          f32x2 s = *(const f32x2*)&wiS[4 * H3_ + g * 64 + hb2];   // bias
#pragma unroll
          for (int kk = 0; kk < 4; ++kk) {
            f32x2 wv = *(const f32x2*)&wiS[kk * H3_ + g * 64 + hb2];
            s += xv[r][kk] * wv;
          }
          gi[g] = s;
        }
#pragma unroll
        for (int c2 = 0; c2 < 2; ++c2) {
          const int cg = 2 * hh + c2;
          float rg = sigm_fast(gi[0][c2] + acc[c2][r]);
          float zg = sigm_fast(gi[1][c2] + acc[2 + c2][r]);
          float ng = tanh_fast(gi[2][c2] + rg * (acc[4 + c2][r] + bhnr[cg]));
          float nc = zg * (cf[r][cg] - ng) + ng;   // (1-z)n + z*c
          cf[r][cg] = nc;
        }
      }
    }

    // single store phase per t from cf
#pragma unroll
    for (int r = 0; r < 4; ++r) {
      const int row = 16 * w + 4 * hi4 + r;
      const int node = nbase + row;
      u64 pk = 0;
#pragma unroll
      for (int e = 0; e < 4; ++e) pk |= (u64)f2b(cf[r][e]) << (16 * e);
      *(u64*)&hs[(size_t)((t * B_ + b) * N_ + node) * H_ + hb] = pk;
      *(u64*)&carry[row * 72 + hb] = pk;
      if (t == T_ - 1)
        *(f32x4*)&hfin[(size_t)(b * N_ + node) * H_ + hb] = cf[r];
    }
    // no __syncthreads: carry rows are wave-private, whT/wiS read-only
  }
}

// ---------------------------------------------------------------------------
// Kernel 2 v5: back to the 8-slice loop (grid 1024; R4-proven faster than
// R5's one-slice split) + f32 LDS for Q/K (kills the 36 f2b + 108 b2f
// format-shuffle VALU ops/thread that R5's counters showed as the cost:
// VALUBusy 58%, MfmaUtil 9.5%, HBM 16%). V stays bf16 so LDS = 38.9 KB ->
// 4 blocks/CU. Gather geometry hoisted: per-slice prefetch = 3 flat loads
// off a scalar base. Wo output unchanged (coalesced bf16, no atomics).
// ---------------------------------------------------------------------------
__global__ __launch_bounds__(256) void k_attn(
    const int tb0,
    const unsigned short* __restrict__ hs,    // [T*B,N,H] bf16
    const int* __restrict__ indices,
    const unsigned short* __restrict__ wT,    // [4][64][64] bf16
    const float* __restrict__ bq, const float* __restrict__ bk,
    const float* __restrict__ bv, const float* __restrict__ bo,
    unsigned short* __restrict__ a_edge)      // [8,NE,H] bf16
{
  __shared__ __align__(16) unsigned short bufrag[3072]; // 6144 B, A/o frags
  __shared__ __align__(16) float qs[48 * 68];           // 13056 B
  __shared__ __align__(16) float ksh[48 * 68];          // 13056 B
  __shared__ __align__(8)  unsigned short vs[48 * 68];  // 6528 B
  __shared__ int idxs[48];

  const int tid = threadIdx.x;
  const int lane = tid & 63;
  const int w = tid >> 6;
  const int c15 = lane & 15;
  const int hi4 = lane >> 4;
  const int bid = blockIdx.x;
  const int col = 16 * w + c15;
  const int swz = (c15 ^ (hi4 << 2));         // swizzled frag-read row

  if (tid < 48) idxs[tid] = indices[bid * 48 + tid];

  // per-wave B fragments: one contiguous 16-B load each from wT
  s16x8 wB[3][2], wB3[2];
#pragma unroll
  for (int m = 0; m < 3; ++m)
#pragma unroll
    for (int ks = 0; ks < 2; ++ks)
      wB[m][ks] = *(const s16x8*)&wT[(m * 64 + col) * 64 + ks * 32 + hi4 * 8];
#pragma unroll
  for (int ks = 0; ks < 2; ++ks)
    wB3[ks] = *(const s16x8*)&wT[(3 * 64 + col) * 64 + ks * 32 + hi4 * 8];
  const float bq_c = bq[col], bk_c = bk[col], bv_c = bv[col], bo_c = bo[col];
  __syncthreads();                            // idxs ready

  // gather geometry: thread covers rows grow, grow+16, grow+32 at group gg;
  // all loop-invariant -> element offsets + swizzled bufrag offsets in regs.
  const int grow = tid >> 4, gg = tid & 15;
  const int gks = gg >> 3, gh5 = (gg >> 1) & 3, gj = (gg & 1) * 4;
  size_t goff[3];
  int boff[3];
#pragma unroll
  for (int k = 0; k < 3; ++k) {
    goff[k] = (size_t)idxs[grow + k * 16] * H_ + gg * 4;
    int cr2 = grow ^ (gh5 << 2);              // rt == k, cr == grow
    boff[k] = ((k * 2 + gks) << 9) + ((gh5 * 16 + cr2) << 3) + gj;
  }

  // prefetch slice 0
  u64 pf[3];
  {
    const unsigned short* hp = hs + (size_t)tb0 * (N_ * H_);
#pragma unroll
    for (int k = 0; k < 3; ++k) pf[k] = *(const u64*)&hp[goff[k]];
  }

  for (int it = 0; it < 8; ++it) {
    __syncthreads();                          // B0: prev Wo bufrag reads done
#pragma unroll
    for (int k = 0; k < 3; ++k) *(u64*)&bufrag[boff[k]] = pf[k];
    __syncthreads();                          // B1

    // ---- QKV projections: q,k stored f32 (no converts), v bf16 ----
    s16x8 afr[3][2];
#pragma unroll
    for (int rt = 0; rt < 3; ++rt)
#pragma unroll
      for (int ks = 0; ks < 2; ++ks)
        afr[rt][ks] = *(const s16x8*)&bufrag[((rt * 2 + ks) << 9) + ((hi4 * 16 + swz) << 3)];
#pragma unroll
    for (int rt = 0; rt < 3; ++rt) {
      f32x4 aq = (f32x4){0.f, 0.f, 0.f, 0.f};
      aq = __builtin_amdgcn_mfma_f32_16x16x32_bf16(afr[rt][0], wB[0][0], aq, 0, 0, 0);
      aq = __builtin_amdgcn_mfma_f32_16x16x32_bf16(afr[rt][1], wB[0][1], aq, 0, 0, 0);
#pragma unroll
      for (int r = 0; r < 4; ++r)
        qs[(16 * rt + hi4 * 4 + r) * 68 + col] = (aq[r] + bq_c) * 0.25f;
    }
#pragma unroll
    for (int rt = 0; rt < 3; ++rt) {
      f32x4 ak = (f32x4){0.f, 0.f, 0.f, 0.f};
      ak = __builtin_amdgcn_mfma_f32_16x16x32_bf16(afr[rt][0], wB[1][0], ak, 0, 0, 0);
      ak = __builtin_amdgcn_mfma_f32_16x16x32_bf16(afr[rt][1], wB[1][1], ak, 0, 0, 0);
#pragma unroll
      for (int r = 0; r < 4; ++r)
        ksh[(16 * rt + hi4 * 4 + r) * 68 + col] = ak[r] + bk_c;
    }
#pragma unroll
    for (int rt = 0; rt < 3; ++rt) {
      f32x4 av = (f32x4){0.f, 0.f, 0.f, 0.f};
      av = __builtin_amdgcn_mfma_f32_16x16x32_bf16(afr[rt][0], wB[2][0], av, 0, 0, 0);
      av = __builtin_amdgcn_mfma_f32_16x16x32_bf16(afr[rt][1], wB[2][1], av, 0, 0, 0);
#pragma unroll
      for (int r = 0; r < 4; ++r)
        vs[(16 * rt + hi4 * 4 + r) * 68 + col] = f2b(av[r] + bv_c);
    }
    // prefetch next slice (flat loads off scalar base)
    if (it < 7) {
      const unsigned short* hp = hs + (size_t)(tb0 + it + 1) * (N_ * H_);
#pragma unroll
      for (int k = 0; k < 3; ++k) pf[k] = *(const u64*)&hp[goff[k]];
    }
    __syncthreads();                          // B2

    // ---- softmax + PV: thread = (f, head, dq); f32x4 q/k reads ----
    {
      int f = tid >> 4, head = (tid >> 2) & 3, dq = tid & 3;
      int colb = head * 16 + dq * 4;
      f32x4 qv[3], kv[3];
      float vv[3][4];
#pragma unroll
      for (int qi = 0; qi < 3; ++qi) {
        int base = (3 * f + qi) * 68 + colb;
        qv[qi] = *(const f32x4*)&qs[base];
        kv[qi] = *(const f32x4*)&ksh[base];
        u64 uv = *(const u64*)&vs[base];
#pragma unroll
        for (int e = 0; e < 4; ++e)
          vv[qi][e] = b2f((unsigned short)(uv >> (16 * e)));
      }
      float s[3][3];
#pragma unroll
      for (int qi = 0; qi < 3; ++qi)
#pragma unroll
        for (int ki = 0; ki < 3; ++ki) {
          float a = qv[qi][0] * kv[ki][0] + qv[qi][1] * kv[ki][1]
                  + qv[qi][2] * kv[ki][2] + qv[qi][3] * kv[ki][3];
          a += __shfl_xor(a, 1, 64);
          a += __shfl_xor(a, 2, 64);
          s[qi][ki] = a;
        }
      const int ks2 = colb >> 5, h5b = (colb >> 3) & 3, jb = colb & 7;
#pragma unroll
      for (int qi = 0; qi < 3; ++qi) {
        float mx = fmaxf(s[qi][0], fmaxf(s[qi][1], s[qi][2]));
        float e0 = __expf(s[qi][0] - mx), e1 = __expf(s[qi][1] - mx), e2 = __expf(s[qi][2] - mx);
        float inv = 1.f / (e0 + e1 + e2);
        e0 *= inv; e1 *= inv; e2 *= inv;
        int row = 3 * f + qi;
        int rt = row >> 4, cr2 = (row & 15) ^ (h5b << 2);
        u64 pack = 0;
#pragma unroll
        for (int e = 0; e < 4; ++e) {
          float o = e0 * vv[0][e] + e1 * vv[1][e] + e2 * vv[2][e];
          pack |= (u64)f2b(o) << (16 * e);
        }
        *(u64*)&bufrag[((rt * 2 + ks2) << 9) + ((h5b * 16 + cr2) << 3) + jb] = pack;
      }
    }
    __syncthreads();                          // B3

    // ---- a = o @ Wo + bo, coalesced bf16 store (NO atomics) ----
    {
      const size_t abase = (size_t)it * NE_ + (size_t)bid * 48;
#pragma unroll
      for (int rt = 0; rt < 3; ++rt) {
        s16x8 o0 = *(const s16x8*)&bufrag[((rt * 2 + 0) << 9) + ((hi4 * 16 + swz) << 3)];
        s16x8 o1 = *(const s16x8*)&bufrag[((rt * 2 + 1) << 9) + ((hi4 * 16 + swz) << 3)];
        f32x4 acc = (f32x4){0.f, 0.f, 0.f, 0.f};
        acc = __builtin_amdgcn_mfma_f32_16x16x32_bf16(o0, wB3[0], acc, 0, 0, 0);
        acc = __builtin_amdgcn_mfma_f32_16x16x32_bf16(o1, wB3[1], acc, 0, 0, 0);
#pragma unroll
        for (int r = 0; r < 4; ++r) {
          int row = 16 * rt + hi4 * 4 + r;
          a_edge[(abase + row) * H_ + col] = f2b(acc[r] + bo_c);
        }
      }
    }
  }
}

// ---------------------------------------------------------------------------
// Kernel 3 v2 (verified R4/R5): one half (8 tb). LDS-staged elist +
// branchless UF=8 predicated gather. Grid 2048 = 8 ls x 256.
// ---------------------------------------------------------------------------
__global__ __launch_bounds__(256) void k_head(
    const int tb0,
    const unsigned short* __restrict__ a_edge, // [8,NE,H] bf16
    const int* __restrict__ offs, const int* __restrict__ elist,
    const float* __restrict__ nnz,
    const float* __restrict__ extra,
    const float* __restrict__ W1, const float* __restrict__ b1,
    const float* __restrict__ W2, const float* __restrict__ b2,
    float* __restrict__ yg,                    // [T*B,KALL,H] f32, pre-zeroed
    float* __restrict__ logit)                 // [T,B,N] f32
{
  __shared__ short w1T[64 * STR];
  __shared__ short arow[64 * STR];
  __shared__ int offsS[65];
  __shared__ int eidS[512];
  __shared__ float hEx[64];
  __shared__ float w2s[64];
  __shared__ float red[4][64];

  const int tid = threadIdx.x;
  const int lane = tid & 63;
  const int w = tid >> 6;
  const int c15 = lane & 15;
  const int hi4 = lane >> 4;
  const int bid = blockIdx.x;
  const int ls = bid >> 8;             // local slice 0..7
  const int tb = tb0 + ls;
  const int nbase = (bid & 255) * 64;
  const int kall = nbase >> 12;

  for (int i = tid; i < 4096; i += 256) {
    int k = i >> 6, colc = i & 63;
    w1T[colc * STR + k] = (short)f2b(W1[i]);
  }
  if (tid < 65) offsS[tid] = offs[nbase + tid];
  if (tid < 64) {
    float s = b1[tid];
#pragma unroll
    for (int e = 0; e < 4; ++e)
      s += extra[(tb * KALL_ + kall) * DE_ + e] * W1[(64 + e) * 64 + tid];
    hEx[tid] = s;
    w2s[tid] = W2[tid];
  }
  // edge-range staging (every thread loads the two bounds directly: no
  // barrier dependency on offsS)
  const int ebeg = offs[nbase];
  const int ecnt = offs[nbase + 64] - ebeg;
  const bool fast = (ecnt <= 512);
  if (tid == 0) eidS[0] = 0;           // safe dup slot even when ecnt == 0
  if (fast) {
    for (int j = tid; j < ecnt; j += 256) eidS[j] = elist[ebeg + j];
  }
  __syncthreads();

  const size_t ebase = (size_t)ls * NE_;
  float accp = 0.f;
  if (fast) {
    for (int r = w; r < 64; r += 4) {
      const int beg = offsS[r] - ebeg, end = offsS[r + 1] - ebeg;
      float s = 0.f;
#pragma unroll
      for (int u = 0; u < 8; ++u) {
        int p = beg + u;
        bool valid = p < end;
        int pc = valid ? p : 0;        // dup -> eidS[0], L1-hot row
        float v = b2f(a_edge[(ebase + eidS[pc]) * H_ + lane]);
        s += valid ? v : 0.f;
      }
      for (int p = beg + 8; p < end; ++p)          // rare tail (cnt > 8)
        s += b2f(a_edge[(ebase + eidS[p]) * H_ + lane]);
      float val = s / fmaxf((float)(end - beg), 1.f);
      accp += val;
      arow[r * STR + lane] = (short)f2b(val);
    }
  } else {
    // fallback: direct-global dynamic loop (never taken for this input size)
    for (int r = w; r < 64; r += 4) {
      const int beg = offsS[r], end = offsS[r + 1];
      float s = 0.f;
      for (int p = beg; p < end; ++p)
        s += b2f(a_edge[(ebase + elist[p]) * H_ + lane]);
      float val = s / fmaxf((float)(end - beg), 1.f);
      accp += val;
      arow[r * STR + lane] = (short)f2b(val);
    }
  }
  red[w][lane] = accp;
  __syncthreads();

  f32x4 acc[4];
#pragma unroll
  for (int ct = 0; ct < 4; ++ct) acc[ct] = (f32x4){0.f, 0.f, 0.f, 0.f};
#pragma unroll
  for (int ks = 0; ks < 2; ++ks) {
    int kb = ks * 32 + hi4 * 8;
    s16x8 af = *(const s16x8*)&arow[(16 * w + c15) * STR + kb];
#pragma unroll
    for (int ct = 0; ct < 4; ++ct) {
      s16x8 bfr = *(const s16x8*)&w1T[(16 * ct + c15) * STR + kb];
      acc[ct] = __builtin_amdgcn_mfma_f32_16x16x32_bf16(af, bfr, acc[ct], 0, 0, 0);
    }
  }
  const float b2v = b2[0];
#pragma unroll
  for (int r = 0; r < 4; ++r) {
    float s = 0.f;
#pragma unroll
    for (int ct = 0; ct < 4; ++ct) {
      int colc = 16 * ct + c15;
      s += fmaxf(acc[ct][r] + hEx[colc], 0.f) * w2s[colc];
    }
    s += __shfl_xor(s, 1, 64);
    s += __shfl_xor(s, 2, 64);
    s += __shfl_xor(s, 4, 64);
    s += __shfl_xor(s, 8, 64);
    if (c15 == 0)
      logit[tb * N_ + nbase + 16 * w + hi4 * 4 + r] = s + b2v;
  }
  if (tid < 64) {
    float sv = red[0][tid] + red[1][tid] + red[2][tid] + red[3][tid];
    atomicAdd(&yg[(tb * KALL_ + kall) * H_ + tid], sv);
  }
}

// ---------------------------------------------------------------------------
// Kernel 4: value head + h_global passthrough (f32)
// ---------------------------------------------------------------------------
__global__ __launch_bounds__(256) void k_final(
    const float* __restrict__ yg,
    const float* __restrict__ extra,
    const float* __restrict__ Wv1, const float* __restrict__ bv1,
    const float* __restrict__ hg_in,
    float* __restrict__ value_out,
    float* __restrict__ hg_out)
{
  const int tid = threadIdx.x;
  if (tid < 16) {
    const float bv = bv1[0];
    float v = 0.f;
    for (int kall = 0; kall < 4; ++kall) {
      float s = bv;
      for (int hh = 0; hh < 64; ++hh)
        s += (yg[(tid * KALL_ + kall) * H_ + hh] * (1.f / 4096.f)) * Wv1[hh];
      for (int e = 0; e < 4; ++e)
        s += extra[(tid * KALL_ + kall) * DE_ + e] * Wv1[64 + e];
      v += s;
    }
    value_out[tid] = v;
  }
  for (int i = tid; i < 1024; i += 256) hg_out[i] = hg_in[i];
}

// ---------------------------------------------------------------------------
// Workspace layout (84.4 MB, proven safe):
//   yg     @ 0        : 16,384 B    f32 [T*B,KALL,H]
//   cnt    @ 16384    : 65,536 B    int [N]
//   offs   @ 81920    : 65,540 B    int [N+1]
//   cursor @ 147584   : 65,536 B    int [N]
//   elist  @ 213120   : 196,608 B   int [NE]
//   whTg   @ 409728   : 24,576 B    bf16 [192][64] permuted WhT
//   wT     @ 434304   : 32,768 B    bf16 [4][64][64] transposed Wq/Wk/Wv/Wo
//   hs     @ 524288   : 33,554,432 B bf16 [T*B,N,H]
//   a_edge @ 34078720 : 50,331,648 B bf16 [8,NE,H]  (reused per half)
// ---------------------------------------------------------------------------
extern "C" void kernel_launch(void* const* d_in, const int* in_sizes, int n_in,
                              void* d_out, int out_size, void* d_ws, size_t ws_size,
                              hipStream_t stream)
{
  (void)in_sizes; (void)n_in; (void)out_size; (void)ws_size;
  const float* h0    = (const float*)d_in[0];
  const float* hg    = (const float*)d_in[1];
  const float* x     = (const float*)d_in[2];
  const float* extra = (const float*)d_in[3];
  const int*   dn    = (const int*)d_in[4];
  const int*   idx   = (const int*)d_in[5];
  const float* nnz   = (const float*)d_in[6];
  const float* Wi    = (const float*)d_in[7];
  const float* bi    = (const float*)d_in[8];
  const float* Wh    = (const float*)d_in[9];
  const float* bhn   = (const float*)d_in[10];
  const float* Wq    = (const float*)d_in[11];
  const float* bq    = (const float*)d_in[12];
  const float* Wk    = (const float*)d_in[13];
  const float* bk    = (const float*)d_in[14];
  const float* Wv    = (const float*)d_in[15];
  const float* bv    = (const float*)d_in[16];
  const float* Wo    = (const float*)d_in[17];
  const float* bo    = (const float*)d_in[18];
  const float* W1    = (const float*)d_in[19];
  const float* b1    = (const float*)d_in[20];
  const float* W2    = (const float*)d_in[21];
  const float* b2    = (const float*)d_in[22];
  const float* Wv1   = (const float*)d_in[23];
  const float* bv1   = (const float*)d_in[24];

  float* out = (float*)d_out;
  float* out_hfin  = out;                 // [B,N,H]    4194304
  float* out_hg    = out + 4194304;       // [B,K,DOUT]    1024
  float* out_logit = out + 4195328;       // [T,B,N]     262144
  float* out_value = out + 4457472;       // [T,B]           16

  char* wsb = (char*)d_ws;
  float*          yg     = (float*)wsb;
  int*            cnt    = (int*)(wsb + 16384);
  int*            offs   = (int*)(wsb + 81920);
  int*            cursor = (int*)(wsb + 147584);
  int*            elist  = (int*)(wsb + 213120);
  unsigned short* whTg   = (unsigned short*)(wsb + 409728);
  unsigned short* wT     = (unsigned short*)(wsb + 434304);
  unsigned short* hs     = (unsigned short*)(wsb + 524288);
  unsigned short* a_edge = (unsigned short*)(wsb + 34078720);

  hipMemsetAsync(wsb, 0, 81920, stream);      // yg + cnt
  k_prep<<<304, 256, 0, stream>>>(idx, cnt, Wh, whTg, Wq, Wk, Wv, Wo, wT);
  k_csr_scan<<<1, 256, 0, stream>>>(cnt, offs, cursor);
  k_csr_fill<<<192, 256, 0, stream>>>(idx, cursor, elist);
  k_gru<<<1024, 256, 0, stream>>>(h0, x, dn, whTg, Wi, bi, bhn, hs, out_hfin);
  for (int half = 0; half < 2; ++half) {
    const int tb0 = half * 8;
    k_attn<<<1024, 256, 0, stream>>>(tb0, hs, idx, wT, bq, bk, bv, bo, a_edge);
    k_head<<<2048, 256, 0, stream>>>(tb0, a_edge, offs, elist, nnz, extra,
                                     W1, b1, W2, b2, yg, out_logit);
  }
  k_final<<<1, 256, 0, stream>>>(yg, extra, Wv1, bv1, hg, out_value, out_hg);
}

// Round 7
// 332.269 us; speedup vs baseline: 1.0185x; 1.0060x over previous
//
#include <hip/hip_runtime.h>
#include <hip/hip_bf16.h>

#define T_ 4
#define B_ 4
#define N_ 16384
#define KALL_ 4
#define F_ 16384
#define ORD_ 3
#define DIN_ 4
#define H_ 64
#define H3_ 192
#define DE_ 4
#define STR 72   // padded bf16 leading-dim for MFMA A/B LDS tiles (k_head)
#define NE_ 49152  // F*ORD edges

typedef __attribute__((ext_vector_type(8))) short s16x8;
typedef __attribute__((ext_vector_type(4))) float f32x4;
typedef __attribute__((ext_vector_type(2))) float f32x2;
typedef unsigned long long u64;

static __device__ __forceinline__ float b2f(unsigned short u) {
  union { unsigned u; float f; } x; x.u = ((unsigned)u) << 16; return x.f;
}
static __device__ __forceinline__ unsigned short f2b(float f) {
  __hip_bfloat16 h = __float2bfloat16(f);  // RNE
  union { __hip_bfloat16 h; unsigned short u; } x; x.h = h; return x.u;
}
static __device__ __forceinline__ float sigm_fast(float v) {
  return __builtin_amdgcn_rcpf(1.f + __expf(-v));
}
static __device__ __forceinline__ float tanh_fast(float v) {
  float e = __expf(2.f * v);
  return 1.f - 2.f * __builtin_amdgcn_rcpf(e + 1.f);
}

// ---------------------------------------------------------------------------
// Fused prep: CSR count (blocks 0..191) + Wh permute/convert (192..239) +
// attn-weight transpose/convert (240..303).
// ---------------------------------------------------------------------------
__global__ __launch_bounds__(256) void k_prep(
    const int* __restrict__ idx, int* __restrict__ cnt,
    const float* __restrict__ Wh, unsigned short* __restrict__ whTg,
    const float* __restrict__ Wq, const float* __restrict__ Wk,
    const float* __restrict__ Wv, const float* __restrict__ Wo,
    unsigned short* __restrict__ wT) {
  const int b = blockIdx.x, tid = threadIdx.x;
  if (b < 192) {
    int e = b * 256 + tid;
    if (e < NE_) atomicAdd(&cnt[idx[e]], 1);
  } else if (b < 240) {
    // whTg[rr*64+k], rr=16*ct+c, ct=g*4+cg holds Wh[k][g*64+4*c+cg]
    int i = (b - 192) * 256 + tid;        // 48*256 = 12288
    int rr = i >> 6, k = i & 63;
    int ct = rr >> 4, c = rr & 15;
    int g = ct >> 2, cg = ct & 3;
    whTg[i] = f2b(Wh[k * H3_ + g * 64 + 4 * c + cg]);
  } else {
    // wT[m][col][k] so a per-lane B-fragment is one contiguous 16-B load
    int i = (b - 240) * 256 + tid;        // 64*256 = 16384
    int m = i >> 12, col = (i >> 6) & 63, k = i & 63;
    const float* Wm = (m == 0) ? Wq : (m == 1) ? Wk : (m == 2) ? Wv : Wo;
    wT[i] = f2b(Wm[k * 64 + col]);
  }
}

__global__ __launch_bounds__(256) void k_csr_scan(
    const int* __restrict__ cnt, int* __restrict__ offs, int* __restrict__ cursor) {
  __shared__ int part[256];
  __shared__ int base[256];
  int t = threadIdx.x;
  int s = 0;
  for (int j = 0; j < 64; ++j) s += cnt[t * 64 + j];
  part[t] = s;
  __syncthreads();
  if (t == 0) {
    int run = 0;
    for (int i = 0; i < 256; ++i) { base[i] = run; run += part[i]; }
  }
  __syncthreads();
  int run = base[t];
  for (int j = 0; j < 64; ++j) {
    offs[t * 64 + j] = run;
    cursor[t * 64 + j] = run;
    run += cnt[t * 64 + j];
  }
  if (t == 255) offs[N_] = run;
}
__global__ __launch_bounds__(256) void k_csr_fill(
    const int* __restrict__ idx, int* __restrict__ cursor, int* __restrict__ elist) {
  int e = blockIdx.x * 256 + threadIdx.x;
  if (e < NE_) {
    int pos = atomicAdd(&cursor[idx[e]], 1);
    elist[pos] = e;
  }
}

// ---------------------------------------------------------------------------
// Kernel 1: GRU v4 = v3 + `#pragma unroll 1` on the t-loop. R6 counters:
// VGPR=140 (3 blocks/CU, occupancy 9%) because the fully-unrolled t-loop let
// the compiler keep 4 iterations' state live. The t-loop is data-serial
// anyway; unroll 1 shrinks live ranges -> target <=128 VGPR, 4 blocks/CU.
// ---------------------------------------------------------------------------
__global__ __launch_bounds__(256) void k_gru(
    const float* __restrict__ h0,
    const float* __restrict__ x,
    const int* __restrict__ dones,
    const unsigned short* __restrict__ whTg,
    const float* __restrict__ Wi,
    const float* __restrict__ bi,
    const float* __restrict__ bhn,
    unsigned short* __restrict__ hs,     // [T*B,N,H] bf16
    float* __restrict__ hfin)            // [B,N,H] f32
{
  __shared__ __align__(16) short whT[H3_ * 72];    // 27648 B, bf16 B-tiles
  __shared__ __align__(16) short carry[H_ * 72];   // 9216 B, bf16 A-tiles
  __shared__ float wiS[5 * H3_];                   // 3840 B: Wi rows 0..3, bi row 4

  const int tid = threadIdx.x;
  const int lane = tid & 63;
  const int w = tid >> 6;
  const int c15 = lane & 15;
  const int hi4 = lane >> 4;
  const int bid = blockIdx.x;
  const int b = bid >> 8;
  const int nbase = (bid & 255) * 64;
  const int hb = 4 * c15;                 // contiguous h-base of this lane

  // stage whT (pre-converted, permuted): 6 x 16-byte copies per thread
#pragma unroll
  for (int c = 0; c < 6; ++c) {
    int lin = (c * 256 + tid) * 8;        // element index, 8 bf16 per copy
    int row = lin >> 6, col = lin & 63;
    *(s16x8*)&whT[row * 72 + col] = *(const s16x8*)&whTg[lin];
  }
  // stage Wi (f32) + bias row
  for (int i = tid; i < 5 * H3_; i += 256)
    wiS[i] = (i < 4 * H3_) ? Wi[i] : bi[i - 4 * H3_];

  // carry state in registers + bf16 LDS copy (wave-private rows)
  f32x4 cf[4];
#pragma unroll
  for (int r = 0; r < 4; ++r) {
    int row = 16 * w + 4 * hi4 + r;
    cf[r] = *(const f32x4*)&h0[(size_t)(b * N_ + nbase + row) * H_ + hb];
    u64 pk = 0;
#pragma unroll
    for (int e = 0; e < 4; ++e) pk |= (u64)f2b(cf[r][e]) << (16 * e);
    *(u64*)&carry[row * 72 + hb] = pk;
  }

  float bhnr[4];
#pragma unroll
  for (int cg = 0; cg < 4; ++cg) bhnr[cg] = bhn[hb + cg];

  // hoisted dones decode -> bitmask (no runtime-indexed array: rule #20)
  unsigned dmask = 0;
  {
    bool word = true;
#pragma unroll
    for (int i = 0; i < 16; ++i) {
      int v = dones[i];
      if (v != 0 && v != 1 && v != 0x3F800000) word = false;
    }
#pragma unroll
    for (int t = 0; t < T_; ++t) {
      int tb = t * B_ + b;
      bool d = word ? (dones[tb] != 0) : (((const unsigned char*)dones)[tb] != 0);
      if (d) dmask |= (1u << t);
    }
  }

  __syncthreads();   // whT/wiS visible; after this the t-loop is barrier-free

  const int rowA = 16 * w + c15;
#pragma unroll 1
  for (int t = 0; t < T_; ++t) {
    if ((dmask >> t) & 1u) {
#pragma unroll
      for (int r = 0; r < 4; ++r) {
        cf[r] = (f32x4){0.f, 0.f, 0.f, 0.f};
        *(u64*)&carry[(16 * w + 4 * hi4 + r) * 72 + hb] = 0ull;
      }
    }

    // A-fragments for this t (carry rows are wave-private; DS ops in-order)
    s16x8 af0 = *(const s16x8*)&carry[rowA * 72 + hi4 * 8];
    s16x8 af1 = *(const s16x8*)&carry[rowA * 72 + 32 + hi4 * 8];

    // x for all 4 rows, loaded early (independent HBM loads)
    f32x4 xv[4];
#pragma unroll
    for (int r = 0; r < 4; ++r) {
      const int node = nbase + 16 * w + 4 * hi4 + r;
      xv[r] = *(const f32x4*)&x[(size_t)((t * B_ + b) * N_ + node) * DIN_];
    }

    // two cg-halves: hh covers output columns hb+2*hh .. hb+2*hh+1
#pragma unroll
    for (int hh = 0; hh < 2; ++hh) {
      f32x4 acc[6];                       // [g*2+c2], only 24 VGPR live
#pragma unroll
      for (int j = 0; j < 6; ++j) acc[j] = (f32x4){0.f, 0.f, 0.f, 0.f};
#pragma unroll
      for (int j = 0; j < 6; ++j) {
        const int ct = (j >> 1) * 4 + 2 * hh + (j & 1);
        acc[j] = __builtin_amdgcn_mfma_f32_16x16x32_bf16(
            af0, *(const s16x8*)&whT[(16 * ct + c15) * 72 + hi4 * 8], acc[j], 0, 0, 0);
      }
#pragma unroll
      for (int j = 0; j < 6; ++j) {
        const int ct = (j >> 1) * 4 + 2 * hh + (j & 1);
        acc[j] = __builtin_amdgcn_mfma_f32_16x16x32_bf16(
            af1, *(const s16x8*)&whT[(16 * ct + c15) * 72 + 32 + hi4 * 8], acc[j], 0, 0, 0);
      }
      const int hb2 = hb + 2 * hh;
#pragma unroll
      for (int r = 0; r < 4; ++r) {
        f32x2 gi[3];
#pragma unroll
        for (int g = 0; g < 3; ++g) {
          f32x2 s = *(const f32x2*)&wiS[4 * H3_ + g * 64 + hb2];   // bias
#pragma unroll
          for (int kk = 0; kk < 4; ++kk) {
            f32x2 wv = *(const f32x2*)&wiS[kk * H3_ + g * 64 + hb2];
            s += xv[r][kk] * wv;
          }
          gi[g] = s;
        }
#pragma unroll
        for (int c2 = 0; c2 < 2; ++c2) {
          const int cg = 2 * hh + c2;
          float rg = sigm_fast(gi[0][c2] + acc[c2][r]);
          float zg = sigm_fast(gi[1][c2] + acc[2 + c2][r]);
          float ng = tanh_fast(gi[2][c2] + rg * (acc[4 + c2][r] + bhnr[cg]));
          float nc = zg * (cf[r][cg] - ng) + ng;   // (1-z)n + z*c
          cf[r][cg] = nc;
        }
      }
    }

    // single store phase per t from cf
#pragma unroll
    for (int r = 0; r < 4; ++r) {
      const int row = 16 * w + 4 * hi4 + r;
      const int node = nbase + row;
      u64 pk = 0;
#pragma unroll
      for (int e = 0; e < 4; ++e) pk |= (u64)f2b(cf[r][e]) << (16 * e);
      *(u64*)&hs[(size_t)((t * B_ + b) * N_ + node) * H_ + hb] = pk;
      *(u64*)&carry[row * 72 + hb] = pk;
      if (t == T_ - 1)
        *(f32x4*)&hfin[(size_t)(b * N_ + node) * H_ + hb] = cf[r];
    }
    // no __syncthreads: carry rows are wave-private, whT/wiS read-only
  }
}

// ---------------------------------------------------------------------------
// Kernel 2 v6: 8-slice loop, f32 Q/K LDS (R6-verified), and NO Wo phase:
// since Wo is linear and the downstream gather-sum is linear,
//   sum(o@Wo+bo)/nnz == (sum o/nnz)@Wo + 1{cnt>0} bo,
// so softmax+PV writes o DIRECTLY to a_edge (128B-coalesced segments) and
// k_head applies Wo. Removes 6 MFMAs + o LDS round-trip + 1 barrier per it
// (4 -> 3 barriers).
// ---------------------------------------------------------------------------
__global__ __launch_bounds__(256) void k_attn(
    const int tb0,
    const unsigned short* __restrict__ hs,    // [T*B,N,H] bf16
    const int* __restrict__ indices,
    const unsigned short* __restrict__ wT,    // [4][64][64] bf16
    const float* __restrict__ bq, const float* __restrict__ bk,
    const float* __restrict__ bv,
    unsigned short* __restrict__ a_edge)      // [8,NE,H] bf16 — o values
{
  __shared__ __align__(16) unsigned short bufrag[3072]; // 6144 B, A frags
  __shared__ __align__(16) float qs[48 * 68];           // 13056 B
  __shared__ __align__(16) float ksh[48 * 68];          // 13056 B
  __shared__ __align__(8)  unsigned short vs[48 * 68];  // 6528 B
  __shared__ int idxs[48];

  const int tid = threadIdx.x;
  const int lane = tid & 63;
  const int w = tid >> 6;
  const int c15 = lane & 15;
  const int hi4 = lane >> 4;
  const int bid = blockIdx.x;
  const int col = 16 * w + c15;
  const int swz = (c15 ^ (hi4 << 2));         // swizzled frag-read row

  if (tid < 48) idxs[tid] = indices[bid * 48 + tid];

  // per-wave B fragments: one contiguous 16-B load each from wT
  s16x8 wB[3][2];
#pragma unroll
  for (int m = 0; m < 3; ++m)
#pragma unroll
    for (int ks = 0; ks < 2; ++ks)
      wB[m][ks] = *(const s16x8*)&wT[(m * 64 + col) * 64 + ks * 32 + hi4 * 8];
  const float bq_c = bq[col], bk_c = bk[col], bv_c = bv[col];
  __syncthreads();                            // idxs ready

  // gather geometry: thread covers rows grow, grow+16, grow+32 at group gg
  const int grow = tid >> 4, gg = tid & 15;
  const int gks = gg >> 3, gh5 = (gg >> 1) & 3, gj = (gg & 1) * 4;
  size_t goff[3];
  int boff[3];
#pragma unroll
  for (int k = 0; k < 3; ++k) {
    goff[k] = (size_t)idxs[grow + k * 16] * H_ + gg * 4;
    int cr2 = grow ^ (gh5 << 2);              // rt == k, cr == grow
    boff[k] = ((k * 2 + gks) << 9) + ((gh5 * 16 + cr2) << 3) + gj;
  }

  // prefetch slice 0
  u64 pf[3];
  {
    const unsigned short* hp = hs + (size_t)tb0 * (N_ * H_);
#pragma unroll
    for (int k = 0; k < 3; ++k) pf[k] = *(const u64*)&hp[goff[k]];
  }

  for (int it = 0; it < 8; ++it) {
#pragma unroll
    for (int k = 0; k < 3; ++k) *(u64*)&bufrag[boff[k]] = pf[k];
    __syncthreads();                          // B1: frags staged

    // ---- QKV projections: q,k stored f32 (no converts), v bf16 ----
    s16x8 afr[3][2];
#pragma unroll
    for (int rt = 0; rt < 3; ++rt)
#pragma unroll
      for (int ks = 0; ks < 2; ++ks)
        afr[rt][ks] = *(const s16x8*)&bufrag[((rt * 2 + ks) << 9) + ((hi4 * 16 + swz) << 3)];
#pragma unroll
    for (int rt = 0; rt < 3; ++rt) {
      f32x4 aq = (f32x4){0.f, 0.f, 0.f, 0.f};
      aq = __builtin_amdgcn_mfma_f32_16x16x32_bf16(afr[rt][0], wB[0][0], aq, 0, 0, 0);
      aq = __builtin_amdgcn_mfma_f32_16x16x32_bf16(afr[rt][1], wB[0][1], aq, 0, 0, 0);
#pragma unroll
      for (int r = 0; r < 4; ++r)
        qs[(16 * rt + hi4 * 4 + r) * 68 + col] = (aq[r] + bq_c) * 0.25f;
    }
#pragma unroll
    for (int rt = 0; rt < 3; ++rt) {
      f32x4 ak = (f32x4){0.f, 0.f, 0.f, 0.f};
      ak = __builtin_amdgcn_mfma_f32_16x16x32_bf16(afr[rt][0], wB[1][0], ak, 0, 0, 0);
      ak = __builtin_amdgcn_mfma_f32_16x16x32_bf16(afr[rt][1], wB[1][1], ak, 0, 0, 0);
#pragma unroll
      for (int r = 0; r < 4; ++r)
        ksh[(16 * rt + hi4 * 4 + r) * 68 + col] = ak[r] + bk_c;
    }
#pragma unroll
    for (int rt = 0; rt < 3; ++rt) {
      f32x4 av = (f32x4){0.f, 0.f, 0.f, 0.f};
      av = __builtin_amdgcn_mfma_f32_16x16x32_bf16(afr[rt][0], wB[2][0], av, 0, 0, 0);
      av = __builtin_amdgcn_mfma_f32_16x16x32_bf16(afr[rt][1], wB[2][1], av, 0, 0, 0);
#pragma unroll
      for (int r = 0; r < 4; ++r)
        vs[(16 * rt + hi4 * 4 + r) * 68 + col] = f2b(av[r] + bv_c);
    }
    // prefetch next slice (flat loads off scalar base)
    if (it < 7) {
      const unsigned short* hp = hs + (size_t)(tb0 + it + 1) * (N_ * H_);
#pragma unroll
      for (int k = 0; k < 3; ++k) pf[k] = *(const u64*)&hp[goff[k]];
    }
    __syncthreads();                          // B2: qkv ready

    // ---- softmax + PV: thread = (f, head, dq); o -> global directly ----
    {
      int f = tid >> 4, head = (tid >> 2) & 3, dq = tid & 3;
      int colb = head * 16 + dq * 4;
      f32x4 qv[3], kv[3];
      float vv[3][4];
#pragma unroll
      for (int qi = 0; qi < 3; ++qi) {
        int base = (3 * f + qi) * 68 + colb;
        qv[qi] = *(const f32x4*)&qs[base];
        kv[qi] = *(const f32x4*)&ksh[base];
        u64 uv = *(const u64*)&vs[base];
#pragma unroll
        for (int e = 0; e < 4; ++e)
          vv[qi][e] = b2f((unsigned short)(uv >> (16 * e)));
      }
      float s[3][3];
#pragma unroll
      for (int qi = 0; qi < 3; ++qi)
#pragma unroll
        for (int ki = 0; ki < 3; ++ki) {
          float a = qv[qi][0] * kv[ki][0] + qv[qi][1] * kv[ki][1]
                  + qv[qi][2] * kv[ki][2] + qv[qi][3] * kv[ki][3];
          a += __shfl_xor(a, 1, 64);
          a += __shfl_xor(a, 2, 64);
          s[qi][ki] = a;
        }
      const size_t abase = (size_t)it * NE_ + (size_t)bid * 48;
#pragma unroll
      for (int qi = 0; qi < 3; ++qi) {
        float mx = fmaxf(s[qi][0], fmaxf(s[qi][1], s[qi][2]));
        float e0 = __expf(s[qi][0] - mx), e1 = __expf(s[qi][1] - mx), e2 = __expf(s[qi][2] - mx);
        float inv = 1.f / (e0 + e1 + e2);
        e0 *= inv; e1 *= inv; e2 *= inv;
        int row = 3 * f + qi;
        u64 pack = 0;
#pragma unroll
        for (int e = 0; e < 4; ++e) {
          float o = e0 * vv[0][e] + e1 * vv[1][e] + e2 * vv[2][e];
          pack |= (u64)f2b(o) << (16 * e);
        }
        *(u64*)&a_edge[(abase + row) * H_ + colb] = pack;
      }
    }
    __syncthreads();                          // B3: qkv/bufrag reusable
  }
}

// ---------------------------------------------------------------------------
// Kernel 3 v3: gather now sums o-values; Wo absorbed here as one extra
// 64x64 MFMA GEMM (B-frags in registers from wT — no extra LDS tile, keeps
// block cap). y = (sum o/nnz)@Wo + 1{cnt>0} bo, then same W1/W2 logit path.
// Wo->W1 phases are barrier-free (wave-private 16-row blocks of arow).
// ---------------------------------------------------------------------------
__global__ __launch_bounds__(256) void k_head(
    const int tb0,
    const unsigned short* __restrict__ a_edge, // [8,NE,H] bf16 — o values
    const int* __restrict__ offs, const int* __restrict__ elist,
    const unsigned short* __restrict__ wT,     // [4][64][64]; m=3 is Wo
    const float* __restrict__ bo,
    const float* __restrict__ extra,
    const float* __restrict__ W1, const float* __restrict__ b1,
    const float* __restrict__ W2, const float* __restrict__ b2,
    float* __restrict__ yg,                    // [T*B,KALL,H] f32, pre-zeroed
    float* __restrict__ logit)                 // [T,B,N] f32
{
  __shared__ short w1T[64 * STR];
  __shared__ short arow[64 * STR];
  __shared__ int offsS[65];
  __shared__ int eidS[512];
  __shared__ float hEx[64];
  __shared__ float w2s[64];
  __shared__ float hasES[64];
  __shared__ float red[4][64];

  const int tid = threadIdx.x;
  const int lane = tid & 63;
  const int w = tid >> 6;
  const int c15 = lane & 15;
  const int hi4 = lane >> 4;
  const int bid = blockIdx.x;
  const int ls = bid >> 8;             // local slice 0..7
  const int tb = tb0 + ls;
  const int nbase = (bid & 255) * 64;
  const int kall = nbase >> 12;

  for (int i = tid; i < 4096; i += 256) {
    int k = i >> 6, colc = i & 63;
    w1T[colc * STR + k] = (short)f2b(W1[i]);
  }
  if (tid < 65) offsS[tid] = offs[nbase + tid];
  if (tid < 64) {
    float s = b1[tid];
#pragma unroll
    for (int e = 0; e < 4; ++e)
      s += extra[(tb * KALL_ + kall) * DE_ + e] * W1[(64 + e) * 64 + tid];
    hEx[tid] = s;
    w2s[tid] = W2[tid];
  }
  // Wo B-fragments + bias in registers (coalesced 16-B loads from wT)
  s16x8 wo_b[2][4];
  float boc[4];
#pragma unroll
  for (int ct = 0; ct < 4; ++ct) {
    boc[ct] = bo[16 * ct + c15];
#pragma unroll
    for (int ks = 0; ks < 2; ++ks)
      wo_b[ks][ct] = *(const s16x8*)&wT[(192 + 16 * ct + c15) * 64 + ks * 32 + hi4 * 8];
  }
  // edge-range staging
  const int ebeg = offs[nbase];
  const int ecnt = offs[nbase + 64] - ebeg;
  const bool fast = (ecnt <= 512);
  if (tid == 0) eidS[0] = 0;           // safe dup slot even when ecnt == 0
  if (fast) {
    for (int j = tid; j < ecnt; j += 256) eidS[j] = elist[ebeg + j];
  }
  __syncthreads();

  const size_t ebase = (size_t)ls * NE_;
  if (fast) {
    for (int r = w; r < 64; r += 4) {
      const int beg = offsS[r] - ebeg, end = offsS[r + 1] - ebeg;
      float s = 0.f;
#pragma unroll
      for (int u = 0; u < 8; ++u) {
        int p = beg + u;
        bool valid = p < end;
        int pc = valid ? p : 0;        // dup -> eidS[0], L1-hot row
        float v = b2f(a_edge[(ebase + eidS[pc]) * H_ + lane]);
        s += valid ? v : 0.f;
      }
      for (int p = beg + 8; p < end; ++p)          // rare tail (cnt > 8)
        s += b2f(a_edge[(ebase + eidS[p]) * H_ + lane]);
      float val = s / fmaxf((float)(end - beg), 1.f);
      arow[r * STR + lane] = (short)f2b(val);
      if (lane == 0) hasES[r] = (end > beg) ? 1.f : 0.f;
    }
  } else {
    // fallback: direct-global dynamic loop (never taken for this input size)
    for (int r = w; r < 64; r += 4) {
      const int beg = offsS[r], end = offsS[r + 1];
      float s = 0.f;
      for (int p = beg; p < end; ++p)
        s += b2f(a_edge[(ebase + elist[p]) * H_ + lane]);
      float val = s / fmaxf((float)(end - beg), 1.f);
      arow[r * STR + lane] = (short)f2b(val);
      if (lane == 0) hasES[r] = (end > beg) ? 1.f : 0.f;
    }
  }
  __syncthreads();

  // ---- Wo GEMM: o-mean -> y; overwrite arow in place (wave-private rows,
  // same-wave DS ordering makes reads-before-writes safe) ----
  f32x4 acco[4];
#pragma unroll
  for (int ct = 0; ct < 4; ++ct) acco[ct] = (f32x4){0.f, 0.f, 0.f, 0.f};
#pragma unroll
  for (int ks = 0; ks < 2; ++ks) {
    int kb = ks * 32 + hi4 * 8;
    s16x8 af = *(const s16x8*)&arow[(16 * w + c15) * STR + kb];
#pragma unroll
    for (int ct = 0; ct < 4; ++ct)
      acco[ct] = __builtin_amdgcn_mfma_f32_16x16x32_bf16(af, wo_b[ks][ct], acco[ct], 0, 0, 0);
  }
  float sumy[4] = {0.f, 0.f, 0.f, 0.f};
#pragma unroll
  for (int r = 0; r < 4; ++r) {
    const int rowr = 16 * w + hi4 * 4 + r;
    const float hase = hasES[rowr];
#pragma unroll
    for (int ct = 0; ct < 4; ++ct) {
      float y = acco[ct][r] + hase * boc[ct];
      arow[rowr * STR + 16 * ct + c15] = (short)f2b(y);
      sumy[ct] += y;
    }
  }
#pragma unroll
  for (int ct = 0; ct < 4; ++ct) {
    sumy[ct] += __shfl_xor(sumy[ct], 16, 64);
    sumy[ct] += __shfl_xor(sumy[ct], 32, 64);
  }
  if (hi4 == 0) {
#pragma unroll
    for (int ct = 0; ct < 4; ++ct) red[w][16 * ct + c15] = sumy[ct];
  }

  // ---- W1 GEMM (reads own wave's arow_y rows; no barrier needed) ----
  f32x4 acc[4];
#pragma unroll
  for (int ct = 0; ct < 4; ++ct) acc[ct] = (f32x4){0.f, 0.f, 0.f, 0.f};
#pragma unroll
  for (int ks = 0; ks < 2; ++ks) {
    int kb = ks * 32 + hi4 * 8;
    s16x8 af = *(const s16x8*)&arow[(16 * w + c15) * STR + kb];
#pragma unroll
    for (int ct = 0; ct < 4; ++ct) {
      s16x8 bfr = *(const s16x8*)&w1T[(16 * ct + c15) * STR + kb];
      acc[ct] = __builtin_amdgcn_mfma_f32_16x16x32_bf16(af, bfr, acc[ct], 0, 0, 0);
    }
  }
  const float b2v = b2[0];
#pragma unroll
  for (int r = 0; r < 4; ++r) {
    float s = 0.f;
#pragma unroll
    for (int ct = 0; ct < 4; ++ct) {
      int colc = 16 * ct + c15;
      s += fmaxf(acc[ct][r] + hEx[colc], 0.f) * w2s[colc];
    }
    s += __shfl_xor(s, 1, 64);
    s += __shfl_xor(s, 2, 64);
    s += __shfl_xor(s, 4, 64);
    s += __shfl_xor(s, 8, 64);
    if (c15 == 0)
      logit[tb * N_ + nbase + 16 * w + hi4 * 4 + r] = s + b2v;
  }
  __syncthreads();
  if (tid < 64) {
    float sv = red[0][tid] + red[1][tid] + red[2][tid] + red[3][tid];
    atomicAdd(&yg[(tb * KALL_ + kall) * H_ + tid], sv);
  }
}

// ---------------------------------------------------------------------------
// Kernel 4: value head + h_global passthrough (f32)
// ---------------------------------------------------------------------------
__global__ __launch_bounds__(256) void k_final(
    const float* __restrict__ yg,
    const float* __restrict__ extra,
    const float* __restrict__ Wv1, const float* __restrict__ bv1,
    const float* __restrict__ hg_in,
    float* __restrict__ value_out,
    float* __restrict__ hg_out)
{
  const int tid = threadIdx.x;
  if (tid < 16) {
    const float bv = bv1[0];
    float v = 0.f;
    for (int kall = 0; kall < 4; ++kall) {
      float s = bv;
      for (int hh = 0; hh < 64; ++hh)
        s += (yg[(tid * KALL_ + kall) * H_ + hh] * (1.f / 4096.f)) * Wv1[hh];
      for (int e = 0; e < 4; ++e)
        s += extra[(tid * KALL_ + kall) * DE_ + e] * Wv1[64 + e];
      v += s;
    }
    value_out[tid] = v;
  }
  for (int i = tid; i < 1024; i += 256) hg_out[i] = hg_in[i];
}

// ---------------------------------------------------------------------------
// Workspace layout (84.4 MB, proven safe):
//   yg     @ 0        : 16,384 B    f32 [T*B,KALL,H]
//   cnt    @ 16384    : 65,536 B    int [N]
//   offs   @ 81920    : 65,540 B    int [N+1]
//   cursor @ 147584   : 65,536 B    int [N]
//   elist  @ 213120   : 196,608 B   int [NE]
//   whTg   @ 409728   : 24,576 B    bf16 [192][64] permuted WhT
//   wT     @ 434304   : 32,768 B    bf16 [4][64][64] transposed Wq/Wk/Wv/Wo
//   hs     @ 524288   : 33,554,432 B bf16 [T*B,N,H]
//   a_edge @ 34078720 : 50,331,648 B bf16 [8,NE,H] o-values (reused per half)
// ---------------------------------------------------------------------------
extern "C" void kernel_launch(void* const* d_in, const int* in_sizes, int n_in,
                              void* d_out, int out_size, void* d_ws, size_t ws_size,
                              hipStream_t stream)
{
  (void)in_sizes; (void)n_in; (void)out_size; (void)ws_size;
  const float* h0    = (const float*)d_in[0];
  const float* hg    = (const float*)d_in[1];
  const float* x     = (const float*)d_in[2];
  const float* extra = (const float*)d_in[3];
  const int*   dn    = (const int*)d_in[4];
  const int*   idx   = (const int*)d_in[5];
  const float* nnz   = (const float*)d_in[6];
  const float* Wi    = (const float*)d_in[7];
  const float* bi    = (const float*)d_in[8];
  const float* Wh    = (const float*)d_in[9];
  const float* bhn   = (const float*)d_in[10];
  const float* Wq    = (const float*)d_in[11];
  const float* bq    = (const float*)d_in[12];
  const float* Wk    = (const float*)d_in[13];
  const float* bk    = (const float*)d_in[14];
  const float* Wv    = (const float*)d_in[15];
  const float* bv    = (const float*)d_in[16];
  const float* Wo    = (const float*)d_in[17];
  const float* bo    = (const float*)d_in[18];
  const float* W1    = (const float*)d_in[19];
  const float* b1    = (const float*)d_in[20];
  const float* W2    = (const float*)d_in[21];
  const float* b2    = (const float*)d_in[22];
  const float* Wv1   = (const float*)d_in[23];
  const float* bv1   = (const float*)d_in[24];
  (void)nnz;

  float* out = (float*)d_out;
  float* out_hfin  = out;                 // [B,N,H]    4194304
  float* out_hg    = out + 4194304;       // [B,K,DOUT]    1024
  float* out_logit = out + 4195328;       // [T,B,N]     262144
  float* out_value = out + 4457472;       // [T,B]           16

  char* wsb = (char*)d_ws;
  float*          yg     = (float*)wsb;
  int*            cnt    = (int*)(wsb + 16384);
  int*            offs   = (int*)(wsb + 81920);
  int*            cursor = (int*)(wsb + 147584);
  int*            elist  = (int*)(wsb + 213120);
  unsigned short* whTg   = (unsigned short*)(wsb + 409728);
  unsigned short* wT     = (unsigned short*)(wsb + 434304);
  unsigned short* hs     = (unsigned short*)(wsb + 524288);
  unsigned short* a_edge = (unsigned short*)(wsb + 34078720);

  hipMemsetAsync(wsb, 0, 81920, stream);      // yg + cnt
  k_prep<<<304, 256, 0, stream>>>(idx, cnt, Wh, whTg, Wq, Wk, Wv, Wo, wT);
  k_csr_scan<<<1, 256, 0, stream>>>(cnt, offs, cursor);
  k_csr_fill<<<192, 256, 0, stream>>>(idx, cursor, elist);
  k_gru<<<1024, 256, 0, stream>>>(h0, x, dn, whTg, Wi, bi, bhn, hs, out_hfin);
  for (int half = 0; half < 2; ++half) {
    const int tb0 = half * 8;
    k_attn<<<1024, 256, 0, stream>>>(tb0, hs, idx, wT, bq, bk, bv, a_edge);
    k_head<<<2048, 256, 0, stream>>>(tb0, a_edge, offs, elist, wT, bo, extra,
                                     W1, b1, W2, b2, yg, out_logit);
  }
  k_final<<<1, 256, 0, stream>>>(yg, extra, Wv1, bv1, hg, out_value, out_hg);
}

// Round 8
// 286.772 us; speedup vs baseline: 1.1801x; 1.1587x over previous
//
#include <hip/hip_runtime.h>
#include <hip/hip_bf16.h>

#define T_ 4
#define B_ 4
#define N_ 16384
#define KALL_ 4
#define F_ 16384
#define ORD_ 3
#define DIN_ 4
#define H_ 64
#define H3_ 192
#define DE_ 4
#define STR 72   // padded bf16 leading-dim for MFMA A/B LDS tiles (k_head)
#define NE_ 49152  // F*ORD edges

typedef __attribute__((ext_vector_type(8))) short s16x8;
typedef __attribute__((ext_vector_type(4))) float f32x4;
typedef __attribute__((ext_vector_type(2))) float f32x2;
typedef unsigned long long u64;

static __device__ __forceinline__ float b2f(unsigned short u) {
  union { unsigned u; float f; } x; x.u = ((unsigned)u) << 16; return x.f;
}
static __device__ __forceinline__ unsigned short f2b(float f) {
  __hip_bfloat16 h = __float2bfloat16(f);  // RNE
  union { __hip_bfloat16 h; unsigned short u; } x; x.h = h; return x.u;
}
static __device__ __forceinline__ float sigm_fast(float v) {
  return __builtin_amdgcn_rcpf(1.f + __expf(-v));
}
static __device__ __forceinline__ float tanh_fast(float v) {
  float e = __expf(2.f * v);
  return 1.f - 2.f * __builtin_amdgcn_rcpf(e + 1.f);
}

// ---------------------------------------------------------------------------
// Fused prep: CSR count (blocks 0..191) + Wh permute/convert (192..239) +
// attn-weight transpose/convert (240..303) + W1 transpose/convert (304..319).
// ---------------------------------------------------------------------------
__global__ __launch_bounds__(256) void k_prep(
    const int* __restrict__ idx, int* __restrict__ cnt,
    const float* __restrict__ Wh, unsigned short* __restrict__ whTg,
    const float* __restrict__ Wq, const float* __restrict__ Wk,
    const float* __restrict__ Wv, const float* __restrict__ Wo,
    unsigned short* __restrict__ wT,
    const float* __restrict__ W1, unsigned short* __restrict__ w1Tg) {
  const int b = blockIdx.x, tid = threadIdx.x;
  if (b < 192) {
    int e = b * 256 + tid;
    if (e < NE_) atomicAdd(&cnt[idx[e]], 1);
  } else if (b < 240) {
    // whTg[rr*64+k], rr=16*ct+c, ct=g*4+cg holds Wh[k][g*64+4*c+cg]
    int i = (b - 192) * 256 + tid;        // 48*256 = 12288
    int rr = i >> 6, k = i & 63;
    int ct = rr >> 4, c = rr & 15;
    int g = ct >> 2, cg = ct & 3;
    whTg[i] = f2b(Wh[k * H3_ + g * 64 + 4 * c + cg]);
  } else if (b < 304) {
    // wT[m][col][k] so a per-lane B-fragment is one contiguous 16-B load
    int i = (b - 240) * 256 + tid;        // 64*256 = 16384
    int m = i >> 12, col = (i >> 6) & 63, k = i & 63;
    const float* Wm = (m == 0) ? Wq : (m == 1) ? Wk : (m == 2) ? Wv : Wo;
    wT[i] = f2b(Wm[k * 64 + col]);
  } else {
    // w1Tg[col*64+k] = W1[k][col], k<64 (extra rows handled via hEx)
    int i = (b - 304) * 256 + tid;        // 16*256 = 4096
    int col = i >> 6, k = i & 63;
    w1Tg[i] = f2b(W1[k * 64 + col]);
  }
}

__global__ __launch_bounds__(256) void k_csr_scan(
    const int* __restrict__ cnt, int* __restrict__ offs, int* __restrict__ cursor) {
  __shared__ int part[256];
  __shared__ int base[256];
  int t = threadIdx.x;
  int s = 0;
  for (int j = 0; j < 64; ++j) s += cnt[t * 64 + j];
  part[t] = s;
  __syncthreads();
  if (t == 0) {
    int run = 0;
    for (int i = 0; i < 256; ++i) { base[i] = run; run += part[i]; }
  }
  __syncthreads();
  int run = base[t];
  for (int j = 0; j < 64; ++j) {
    offs[t * 64 + j] = run;
    cursor[t * 64 + j] = run;
    run += cnt[t * 64 + j];
  }
  if (t == 255) offs[N_] = run;
}
__global__ __launch_bounds__(256) void k_csr_fill(
    const int* __restrict__ idx, int* __restrict__ cursor, int* __restrict__ elist) {
  int e = blockIdx.x * 256 + threadIdx.x;
  if (e < NE_) {
    int pos = atomicAdd(&cursor[idx[e]], 1);
    elist[pos] = e;
  }
}

// ---------------------------------------------------------------------------
// Kernel 1: GRU v5 = v4 + sched_barrier(0) between the two cg-halves.
// Three rounds of counters show the allocator merging both halves' MFMA
// accumulators (VGPR 140-156 -> 3 blocks/CU). The fence blocks instruction
// motion across the half boundary without any semantic change.
// ---------------------------------------------------------------------------
__global__ __launch_bounds__(256) void k_gru(
    const float* __restrict__ h0,
    const float* __restrict__ x,
    const int* __restrict__ dones,
    const unsigned short* __restrict__ whTg,
    const float* __restrict__ Wi,
    const float* __restrict__ bi,
    const float* __restrict__ bhn,
    unsigned short* __restrict__ hs,     // [T*B,N,H] bf16
    float* __restrict__ hfin)            // [B,N,H] f32
{
  __shared__ __align__(16) short whT[H3_ * 72];    // 27648 B, bf16 B-tiles
  __shared__ __align__(16) short carry[H_ * 72];   // 9216 B, bf16 A-tiles
  __shared__ float wiS[5 * H3_];                   // 3840 B: Wi rows 0..3, bi row 4

  const int tid = threadIdx.x;
  const int lane = tid & 63;
  const int w = tid >> 6;
  const int c15 = lane & 15;
  const int hi4 = lane >> 4;
  const int bid = blockIdx.x;
  const int b = bid >> 8;
  const int nbase = (bid & 255) * 64;
  const int hb = 4 * c15;                 // contiguous h-base of this lane

  // stage whT (pre-converted, permuted): 6 x 16-byte copies per thread
#pragma unroll
  for (int c = 0; c < 6; ++c) {
    int lin = (c * 256 + tid) * 8;        // element index, 8 bf16 per copy
    int row = lin >> 6, col = lin & 63;
    *(s16x8*)&whT[row * 72 + col] = *(const s16x8*)&whTg[lin];
  }
  // stage Wi (f32) + bias row
  for (int i = tid; i < 5 * H3_; i += 256)
    wiS[i] = (i < 4 * H3_) ? Wi[i] : bi[i - 4 * H3_];

  // carry state in registers + bf16 LDS copy (wave-private rows)
  f32x4 cf[4];
#pragma unroll
  for (int r = 0; r < 4; ++r) {
    int row = 16 * w + 4 * hi4 + r;
    cf[r] = *(const f32x4*)&h0[(size_t)(b * N_ + nbase + row) * H_ + hb];
    u64 pk = 0;
#pragma unroll
    for (int e = 0; e < 4; ++e) pk |= (u64)f2b(cf[r][e]) << (16 * e);
    *(u64*)&carry[row * 72 + hb] = pk;
  }

  float bhnr[4];
#pragma unroll
  for (int cg = 0; cg < 4; ++cg) bhnr[cg] = bhn[hb + cg];

  // hoisted dones decode -> bitmask (no runtime-indexed array: rule #20)
  unsigned dmask = 0;
  {
    bool word = true;
#pragma unroll
    for (int i = 0; i < 16; ++i) {
      int v = dones[i];
      if (v != 0 && v != 1 && v != 0x3F800000) word = false;
    }
#pragma unroll
    for (int t = 0; t < T_; ++t) {
      int tb = t * B_ + b;
      bool d = word ? (dones[tb] != 0) : (((const unsigned char*)dones)[tb] != 0);
      if (d) dmask |= (1u << t);
    }
  }

  __syncthreads();   // whT/wiS visible; after this the t-loop is barrier-free

  const int rowA = 16 * w + c15;
#pragma unroll 1
  for (int t = 0; t < T_; ++t) {
    if ((dmask >> t) & 1u) {
#pragma unroll
      for (int r = 0; r < 4; ++r) {
        cf[r] = (f32x4){0.f, 0.f, 0.f, 0.f};
        *(u64*)&carry[(16 * w + 4 * hi4 + r) * 72 + hb] = 0ull;
      }
    }

    // A-fragments for this t (carry rows are wave-private; DS ops in-order)
    s16x8 af0 = *(const s16x8*)&carry[rowA * 72 + hi4 * 8];
    s16x8 af1 = *(const s16x8*)&carry[rowA * 72 + 32 + hi4 * 8];

    // x for all 4 rows, loaded early (independent HBM loads)
    f32x4 xv[4];
#pragma unroll
    for (int r = 0; r < 4; ++r) {
      const int node = nbase + 16 * w + 4 * hi4 + r;
      xv[r] = *(const f32x4*)&x[(size_t)((t * B_ + b) * N_ + node) * DIN_];
    }

    // two cg-halves: hh covers output columns hb+2*hh .. hb+2*hh+1
#pragma unroll
    for (int hh = 0; hh < 2; ++hh) {
      f32x4 acc[6];                       // [g*2+c2], only 24 VGPR live
#pragma unroll
      for (int j = 0; j < 6; ++j) acc[j] = (f32x4){0.f, 0.f, 0.f, 0.f};
#pragma unroll
      for (int j = 0; j < 6; ++j) {
        const int ct = (j >> 1) * 4 + 2 * hh + (j & 1);
        acc[j] = __builtin_amdgcn_mfma_f32_16x16x32_bf16(
            af0, *(const s16x8*)&whT[(16 * ct + c15) * 72 + hi4 * 8], acc[j], 0, 0, 0);
      }
#pragma unroll
      for (int j = 0; j < 6; ++j) {
        const int ct = (j >> 1) * 4 + 2 * hh + (j & 1);
        acc[j] = __builtin_amdgcn_mfma_f32_16x16x32_bf16(
            af1, *(const s16x8*)&whT[(16 * ct + c15) * 72 + 32 + hi4 * 8], acc[j], 0, 0, 0);
      }
      const int hb2 = hb + 2 * hh;
#pragma unroll
      for (int r = 0; r < 4; ++r) {
        f32x2 gi[3];
#pragma unroll
        for (int g = 0; g < 3; ++g) {
          f32x2 s = *(const f32x2*)&wiS[4 * H3_ + g * 64 + hb2];   // bias
#pragma unroll
          for (int kk = 0; kk < 4; ++kk) {
            f32x2 wv = *(const f32x2*)&wiS[kk * H3_ + g * 64 + hb2];
            s += xv[r][kk] * wv;
          }
          gi[g] = s;
        }
#pragma unroll
        for (int c2 = 0; c2 < 2; ++c2) {
          const int cg = 2 * hh + c2;
          float rg = sigm_fast(gi[0][c2] + acc[c2][r]);
          float zg = sigm_fast(gi[1][c2] + acc[2 + c2][r]);
          float ng = tanh_fast(gi[2][c2] + rg * (acc[4 + c2][r] + bhnr[cg]));
          float nc = zg * (cf[r][cg] - ng) + ng;   // (1-z)n + z*c
          cf[r][cg] = nc;
        }
      }
      __builtin_amdgcn_sched_barrier(0);  // keep the two halves' regs apart
    }

    // single store phase per t from cf
#pragma unroll
    for (int r = 0; r < 4; ++r) {
      const int row = 16 * w + 4 * hi4 + r;
      const int node = nbase + row;
      u64 pk = 0;
#pragma unroll
      for (int e = 0; e < 4; ++e) pk |= (u64)f2b(cf[r][e]) << (16 * e);
      *(u64*)&hs[(size_t)((t * B_ + b) * N_ + node) * H_ + hb] = pk;
      *(u64*)&carry[row * 72 + hb] = pk;
      if (t == T_ - 1)
        *(f32x4*)&hfin[(size_t)(b * N_ + node) * H_ + hb] = cf[r];
    }
    // no __syncthreads: carry rows are wave-private, whT/wiS read-only
  }
}

// ---------------------------------------------------------------------------
// Kernel 2 v6 (verified R7): 8-slice loop, f32 Q/K LDS, no Wo phase (folded
// into k_head). softmax+PV writes o directly to a_edge.
// ---------------------------------------------------------------------------
__global__ __launch_bounds__(256) void k_attn(
    const int tb0,
    const unsigned short* __restrict__ hs,    // [T*B,N,H] bf16
    const int* __restrict__ indices,
    const unsigned short* __restrict__ wT,    // [4][64][64] bf16
    const float* __restrict__ bq, const float* __restrict__ bk,
    const float* __restrict__ bv,
    unsigned short* __restrict__ a_edge)      // [8,NE,H] bf16 — o values
{
  __shared__ __align__(16) unsigned short bufrag[3072]; // 6144 B, A frags
  __shared__ __align__(16) float qs[48 * 68];           // 13056 B
  __shared__ __align__(16) float ksh[48 * 68];          // 13056 B
  __shared__ __align__(8)  unsigned short vs[48 * 68];  // 6528 B
  __shared__ int idxs[48];

  const int tid = threadIdx.x;
  const int lane = tid & 63;
  const int w = tid >> 6;
  const int c15 = lane & 15;
  const int hi4 = lane >> 4;
  const int bid = blockIdx.x;
  const int col = 16 * w + c15;
  const int swz = (c15 ^ (hi4 << 2));         // swizzled frag-read row

  if (tid < 48) idxs[tid] = indices[bid * 48 + tid];

  // per-wave B fragments: one contiguous 16-B load each from wT
  s16x8 wB[3][2];
#pragma unroll
  for (int m = 0; m < 3; ++m)
#pragma unroll
    for (int ks = 0; ks < 2; ++ks)
      wB[m][ks] = *(const s16x8*)&wT[(m * 64 + col) * 64 + ks * 32 + hi4 * 8];
  const float bq_c = bq[col], bk_c = bk[col], bv_c = bv[col];
  __syncthreads();                            // idxs ready

  // gather geometry: thread covers rows grow, grow+16, grow+32 at group gg
  const int grow = tid >> 4, gg = tid & 15;
  const int gks = gg >> 3, gh5 = (gg >> 1) & 3, gj = (gg & 1) * 4;
  size_t goff[3];
  int boff[3];
#pragma unroll
  for (int k = 0; k < 3; ++k) {
    goff[k] = (size_t)idxs[grow + k * 16] * H_ + gg * 4;
    int cr2 = grow ^ (gh5 << 2);              // rt == k, cr == grow
    boff[k] = ((k * 2 + gks) << 9) + ((gh5 * 16 + cr2) << 3) + gj;
  }

  // prefetch slice 0
  u64 pf[3];
  {
    const unsigned short* hp = hs + (size_t)tb0 * (N_ * H_);
#pragma unroll
    for (int k = 0; k < 3; ++k) pf[k] = *(const u64*)&hp[goff[k]];
  }

  for (int it = 0; it < 8; ++it) {
#pragma unroll
    for (int k = 0; k < 3; ++k) *(u64*)&bufrag[boff[k]] = pf[k];
    __syncthreads();                          // B1: frags staged

    // ---- QKV projections: q,k stored f32 (no converts), v bf16 ----
    s16x8 afr[3][2];
#pragma unroll
    for (int rt = 0; rt < 3; ++rt)
#pragma unroll
      for (int ks = 0; ks < 2; ++ks)
        afr[rt][ks] = *(const s16x8*)&bufrag[((rt * 2 + ks) << 9) + ((hi4 * 16 + swz) << 3)];
#pragma unroll
    for (int rt = 0; rt < 3; ++rt) {
      f32x4 aq = (f32x4){0.f, 0.f, 0.f, 0.f};
      aq = __builtin_amdgcn_mfma_f32_16x16x32_bf16(afr[rt][0], wB[0][0], aq, 0, 0, 0);
      aq = __builtin_amdgcn_mfma_f32_16x16x32_bf16(afr[rt][1], wB[0][1], aq, 0, 0, 0);
#pragma unroll
      for (int r = 0; r < 4; ++r)
        qs[(16 * rt + hi4 * 4 + r) * 68 + col] = (aq[r] + bq_c) * 0.25f;
    }
#pragma unroll
    for (int rt = 0; rt < 3; ++rt) {
      f32x4 ak = (f32x4){0.f, 0.f, 0.f, 0.f};
      ak = __builtin_amdgcn_mfma_f32_16x16x32_bf16(afr[rt][0], wB[1][0], ak, 0, 0, 0);
      ak = __builtin_amdgcn_mfma_f32_16x16x32_bf16(afr[rt][1], wB[1][1], ak, 0, 0, 0);
#pragma unroll
      for (int r = 0; r < 4; ++r)
        ksh[(16 * rt + hi4 * 4 + r) * 68 + col] = ak[r] + bk_c;
    }
#pragma unroll
    for (int rt = 0; rt < 3; ++rt) {
      f32x4 av = (f32x4){0.f, 0.f, 0.f, 0.f};
      av = __builtin_amdgcn_mfma_f32_16x16x32_bf16(afr[rt][0], wB[2][0], av, 0, 0, 0);
      av = __builtin_amdgcn_mfma_f32_16x16x32_bf16(afr[rt][1], wB[2][1], av, 0, 0, 0);
#pragma unroll
      for (int r = 0; r < 4; ++r)
        vs[(16 * rt + hi4 * 4 + r) * 68 + col] = f2b(av[r] + bv_c);
    }
    // prefetch next slice (flat loads off scalar base)
    if (it < 7) {
      const unsigned short* hp = hs + (size_t)(tb0 + it + 1) * (N_ * H_);
#pragma unroll
      for (int k = 0; k < 3; ++k) pf[k] = *(const u64*)&hp[goff[k]];
    }
    __syncthreads();                          // B2: qkv ready

    // ---- softmax + PV: thread = (f, head, dq); o -> global directly ----
    {
      int f = tid >> 4, head = (tid >> 2) & 3, dq = tid & 3;
      int colb = head * 16 + dq * 4;
      f32x4 qv[3], kv[3];
      float vv[3][4];
#pragma unroll
      for (int qi = 0; qi < 3; ++qi) {
        int base = (3 * f + qi) * 68 + colb;
        qv[qi] = *(const f32x4*)&qs[base];
        kv[qi] = *(const f32x4*)&ksh[base];
        u64 uv = *(const u64*)&vs[base];
#pragma unroll
        for (int e = 0; e < 4; ++e)
          vv[qi][e] = b2f((unsigned short)(uv >> (16 * e)));
      }
      float s[3][3];
#pragma unroll
      for (int qi = 0; qi < 3; ++qi)
#pragma unroll
        for (int ki = 0; ki < 3; ++ki) {
          float a = qv[qi][0] * kv[ki][0] + qv[qi][1] * kv[ki][1]
                  + qv[qi][2] * kv[ki][2] + qv[qi][3] * kv[ki][3];
          a += __shfl_xor(a, 1, 64);
          a += __shfl_xor(a, 2, 64);
          s[qi][ki] = a;
        }
      const size_t abase = (size_t)it * NE_ + (size_t)bid * 48;
#pragma unroll
      for (int qi = 0; qi < 3; ++qi) {
        float mx = fmaxf(s[qi][0], fmaxf(s[qi][1], s[qi][2]));
        float e0 = __expf(s[qi][0] - mx), e1 = __expf(s[qi][1] - mx), e2 = __expf(s[qi][2] - mx);
        float inv = 1.f / (e0 + e1 + e2);
        e0 *= inv; e1 *= inv; e2 *= inv;
        int row = 3 * f + qi;
        u64 pack = 0;
#pragma unroll
        for (int e = 0; e < 4; ++e) {
          float o = e0 * vv[0][e] + e1 * vv[1][e] + e2 * vv[2][e];
          pack |= (u64)f2b(o) << (16 * e);
        }
        *(u64*)&a_edge[(abase + row) * H_ + colb] = pack;
      }
    }
    __syncthreads();                          // B3: qkv/bufrag reusable
  }
}

// ---------------------------------------------------------------------------
// Kernel 3 v4: u64 gather — thread = (row, colgroup-of-4) unit, 4 units each;
// 8 predicated u64 loads per unit (was 128 ushort loads/thread -> 32 u64).
// rcp instead of divide; W1 staged from pre-converted w1Tg (2 x 16-B copies).
// Wo absorbed as extra MFMA GEMM (R7-verified).
// ---------------------------------------------------------------------------
__global__ __launch_bounds__(256) void k_head(
    const int tb0,
    const unsigned short* __restrict__ a_edge, // [8,NE,H] bf16 — o values
    const int* __restrict__ offs, const int* __restrict__ elist,
    const unsigned short* __restrict__ wT,     // [4][64][64]; m=3 is Wo
    const float* __restrict__ bo,
    const float* __restrict__ extra,
    const float* __restrict__ W1, const float* __restrict__ b1,
    const unsigned short* __restrict__ w1Tg,   // [64][64] bf16 transposed
    const float* __restrict__ W2, const float* __restrict__ b2,
    float* __restrict__ yg,                    // [T*B,KALL,H] f32, pre-zeroed
    float* __restrict__ logit)                 // [T,B,N] f32
{
  __shared__ __align__(16) short w1T[64 * STR];
  __shared__ __align__(16) short arow[64 * STR];
  __shared__ int offsS[65];
  __shared__ int eidS[512];
  __shared__ float hEx[64];
  __shared__ float w2s[64];
  __shared__ float hasES[64];
  __shared__ float red[4][64];

  const int tid = threadIdx.x;
  const int lane = tid & 63;
  const int w = tid >> 6;
  const int c15 = lane & 15;
  const int hi4 = lane >> 4;
  const int bid = blockIdx.x;
  const int ls = bid >> 8;             // local slice 0..7
  const int tb = tb0 + ls;
  const int nbase = (bid & 255) * 64;
  const int kall = nbase >> 12;

  // stage w1T from pre-converted w1Tg: 2 x 16-B copies per thread
#pragma unroll
  for (int c = 0; c < 2; ++c) {
    int lin = (c * 256 + tid) * 8;
    int row = lin >> 6, col = lin & 63;
    *(s16x8*)&w1T[row * STR + col] = *(const s16x8*)&w1Tg[lin];
  }
  if (tid < 65) offsS[tid] = offs[nbase + tid];
  if (tid < 64) {
    float s = b1[tid];
#pragma unroll
    for (int e = 0; e < 4; ++e)
      s += extra[(tb * KALL_ + kall) * DE_ + e] * W1[(64 + e) * 64 + tid];
    hEx[tid] = s;
    w2s[tid] = W2[tid];
  }
  // Wo B-fragments + bias in registers (coalesced 16-B loads from wT)
  s16x8 wo_b[2][4];
  float boc[4];
#pragma unroll
  for (int ct = 0; ct < 4; ++ct) {
    boc[ct] = bo[16 * ct + c15];
#pragma unroll
    for (int ks = 0; ks < 2; ++ks)
      wo_b[ks][ct] = *(const s16x8*)&wT[(192 + 16 * ct + c15) * 64 + ks * 32 + hi4 * 8];
  }
  // edge-range staging
  const int ebeg = offs[nbase];
  const int ecnt = offs[nbase + 64] - ebeg;
  const bool fast = (ecnt <= 512);
  if (tid == 0) eidS[0] = 0;           // safe dup slot even when ecnt == 0
  if (fast) {
    for (int j = tid; j < ecnt; j += 256) eidS[j] = elist[ebeg + j];
  }
  __syncthreads();

  const size_t ebase = (size_t)ls * NE_;
  if (fast) {
    const int cg = tid & 15;
#pragma unroll
    for (int ku = 0; ku < 4; ++ku) {
      const int r = ku * 16 + (tid >> 4);
      const int beg = offsS[r] - ebeg, end = offsS[r + 1] - ebeg;
      const int cnt = end - beg;
      const float inv = __builtin_amdgcn_rcpf(fmaxf((float)cnt, 1.f));
      f32x4 s = (f32x4){0.f, 0.f, 0.f, 0.f};
#pragma unroll
      for (int u = 0; u < 8; ++u) {
        int p = beg + u;
        bool valid = p < end;
        int pc = valid ? p : 0;        // dup -> eidS[0] row, L1-hot
        u64 v = *(const u64*)&a_edge[(ebase + eidS[pc]) * H_ + cg * 4];
        if (!valid) v = 0;             // 2 cndmasks; b2f(0)=0
        s[0] += b2f((unsigned short)v);
        s[1] += b2f((unsigned short)(v >> 16));
        s[2] += b2f((unsigned short)(v >> 32));
        s[3] += b2f((unsigned short)(v >> 48));
      }
      for (int p = beg + 8; p < end; ++p) {        // rare tail (cnt > 8)
        u64 v = *(const u64*)&a_edge[(ebase + eidS[p]) * H_ + cg * 4];
        s[0] += b2f((unsigned short)v);
        s[1] += b2f((unsigned short)(v >> 16));
        s[2] += b2f((unsigned short)(v >> 32));
        s[3] += b2f((unsigned short)(v >> 48));
      }
      u64 pk = 0;
#pragma unroll
      for (int e = 0; e < 4; ++e) pk |= (u64)f2b(s[e] * inv) << (16 * e);
      *(u64*)&arow[r * STR + cg * 4] = pk;
      if (cg == 0) hasES[r] = (cnt > 0) ? 1.f : 0.f;
    }
  } else {
    // fallback: direct-global dynamic loop (never taken for this input size)
    for (int r = w; r < 64; r += 4) {
      const int beg = offsS[r], end = offsS[r + 1];
      float s = 0.f;
      for (int p = beg; p < end; ++p)
        s += b2f(a_edge[(ebase + elist[p]) * H_ + lane]);
      float val = s / fmaxf((float)(end - beg), 1.f);
      arow[r * STR + lane] = (short)f2b(val);
      if (lane == 0) hasES[r] = (end > beg) ? 1.f : 0.f;
    }
  }
  __syncthreads();

  // ---- Wo GEMM: o-mean -> y; overwrite arow in place (wave-private rows,
  // same-wave DS ordering makes reads-before-writes safe) ----
  f32x4 acco[4];
#pragma unroll
  for (int ct = 0; ct < 4; ++ct) acco[ct] = (f32x4){0.f, 0.f, 0.f, 0.f};
#pragma unroll
  for (int ks = 0; ks < 2; ++ks) {
    int kb = ks * 32 + hi4 * 8;
    s16x8 af = *(const s16x8*)&arow[(16 * w + c15) * STR + kb];
#pragma unroll
    for (int ct = 0; ct < 4; ++ct)
      acco[ct] = __builtin_amdgcn_mfma_f32_16x16x32_bf16(af, wo_b[ks][ct], acco[ct], 0, 0, 0);
  }
  float sumy[4] = {0.f, 0.f, 0.f, 0.f};
#pragma unroll
  for (int r = 0; r < 4; ++r) {
    const int rowr = 16 * w + hi4 * 4 + r;
    const float hase = hasES[rowr];
#pragma unroll
    for (int ct = 0; ct < 4; ++ct) {
      float y = acco[ct][r] + hase * boc[ct];
      arow[rowr * STR + 16 * ct + c15] = (short)f2b(y);
      sumy[ct] += y;
    }
  }
#pragma unroll
  for (int ct = 0; ct < 4; ++ct) {
    sumy[ct] += __shfl_xor(sumy[ct], 16, 64);
    sumy[ct] += __shfl_xor(sumy[ct], 32, 64);
  }
  if (hi4 == 0) {
#pragma unroll
    for (int ct = 0; ct < 4; ++ct) red[w][16 * ct + c15] = sumy[ct];
  }

  // ---- W1 GEMM (reads own wave's arow_y rows; no barrier needed) ----
  f32x4 acc[4];
#pragma unroll
  for (int ct = 0; ct < 4; ++ct) acc[ct] = (f32x4){0.f, 0.f, 0.f, 0.f};
#pragma unroll
  for (int ks = 0; ks < 2; ++ks) {
    int kb = ks * 32 + hi4 * 8;
    s16x8 af = *(const s16x8*)&arow[(16 * w + c15) * STR + kb];
#pragma unroll
    for (int ct = 0; ct < 4; ++ct) {
      s16x8 bfr = *(const s16x8*)&w1T[(16 * ct + c15) * STR + kb];
      acc[ct] = __builtin_amdgcn_mfma_f32_16x16x32_bf16(af, bfr, acc[ct], 0, 0, 0);
    }
  }
  const float b2v = b2[0];
#pragma unroll
  for (int r = 0; r < 4; ++r) {
    float s = 0.f;
#pragma unroll
    for (int ct = 0; ct < 4; ++ct) {
      int colc = 16 * ct + c15;
      s += fmaxf(acc[ct][r] + hEx[colc], 0.f) * w2s[colc];
    }
    s += __shfl_xor(s, 1, 64);
    s += __shfl_xor(s, 2, 64);
    s += __shfl_xor(s, 4, 64);
    s += __shfl_xor(s, 8, 64);
    if (c15 == 0)
      logit[tb * N_ + nbase + 16 * w + hi4 * 4 + r] = s + b2v;
  }
  __syncthreads();
  if (tid < 64) {
    float sv = red[0][tid] + red[1][tid] + red[2][tid] + red[3][tid];
    atomicAdd(&yg[(tb * KALL_ + kall) * H_ + tid], sv);
  }
}

// ---------------------------------------------------------------------------
// Kernel 4: value head + h_global passthrough (f32)
// ---------------------------------------------------------------------------
__global__ __launch_bounds__(256) void k_final(
    const float* __restrict__ yg,
    const float* __restrict__ extra,
    const float* __restrict__ Wv1, const float* __restrict__ bv1,
    const float* __restrict__ hg_in,
    float* __restrict__ value_out,
    float* __restrict__ hg_out)
{
  const int tid = threadIdx.x;
  if (tid < 16) {
    const float bv = bv1[0];
    float v = 0.f;
    for (int kall = 0; kall < 4; ++kall) {
      float s = bv;
      for (int hh = 0; hh < 64; ++hh)
        s += (yg[(tid * KALL_ + kall) * H_ + hh] * (1.f / 4096.f)) * Wv1[hh];
      for (int e = 0; e < 4; ++e)
        s += extra[(tid * KALL_ + kall) * DE_ + e] * Wv1[64 + e];
      v += s;
    }
    value_out[tid] = v;
  }
  for (int i = tid; i < 1024; i += 256) hg_out[i] = hg_in[i];
}

// ---------------------------------------------------------------------------
// Workspace layout (84.4 MB, proven safe):
//   yg     @ 0        : 16,384 B    f32 [T*B,KALL,H]
//   cnt    @ 16384    : 65,536 B    int [N]
//   offs   @ 81920    : 65,540 B    int [N+1]
//   cursor @ 147584   : 65,536 B    int [N]
//   elist  @ 213120   : 196,608 B   int [NE]
//   whTg   @ 409728   : 24,576 B    bf16 [192][64] permuted WhT
//   wT     @ 434304   : 32,768 B    bf16 [4][64][64] transposed Wq/Wk/Wv/Wo
//   w1Tg   @ 467072   : 8,192 B     bf16 [64][64] transposed W1
//   hs     @ 524288   : 33,554,432 B bf16 [T*B,N,H]
//   a_edge @ 34078720 : 50,331,648 B bf16 [8,NE,H] o-values (reused per half)
// ---------------------------------------------------------------------------
extern "C" void kernel_launch(void* const* d_in, const int* in_sizes, int n_in,
                              void* d_out, int out_size, void* d_ws, size_t ws_size,
                              hipStream_t stream)
{
  (void)in_sizes; (void)n_in; (void)out_size; (void)ws_size;
  const float* h0    = (const float*)d_in[0];
  const float* hg    = (const float*)d_in[1];
  const float* x     = (const float*)d_in[2];
  const float* extra = (const float*)d_in[3];
  const int*   dn    = (const int*)d_in[4];
  const int*   idx   = (const int*)d_in[5];
  const float* nnz   = (const float*)d_in[6];
  const float* Wi    = (const float*)d_in[7];
  const float* bi    = (const float*)d_in[8];
  const float* Wh    = (const float*)d_in[9];
  const float* bhn   = (const float*)d_in[10];
  const float* Wq    = (const float*)d_in[11];
  const float* bq    = (const float*)d_in[12];
  const float* Wk    = (const float*)d_in[13];
  const float* bk    = (const float*)d_in[14];
  const float* Wv    = (const float*)d_in[15];
  const float* bv    = (const float*)d_in[16];
  const float* Wo    = (const float*)d_in[17];
  const float* bo    = (const float*)d_in[18];
  const float* W1    = (const float*)d_in[19];
  const float* b1    = (const float*)d_in[20];
  const float* W2    = (const float*)d_in[21];
  const float* b2    = (const float*)d_in[22];
  const float* Wv1   = (const float*)d_in[23];
  const float* bv1   = (const float*)d_in[24];
  (void)nnz;

  float* out = (float*)d_out;
  float* out_hfin  = out;                 // [B,N,H]    4194304
  float* out_hg    = out + 4194304;       // [B,K,DOUT]    1024
  float* out_logit = out + 4195328;       // [T,B,N]     262144
  float* out_value = out + 4457472;       // [T,B]           16

  char* wsb = (char*)d_ws;
  float*          yg     = (float*)wsb;
  int*            cnt    = (int*)(wsb + 16384);
  int*            offs   = (int*)(wsb + 81920);
  int*            cursor = (int*)(wsb + 147584);
  int*            elist  = (int*)(wsb + 213120);
  unsigned short* whTg   = (unsigned short*)(wsb + 409728);
  unsigned short* wT     = (unsigned short*)(wsb + 434304);
  unsigned short* w1Tg   = (unsigned short*)(wsb + 467072);
  unsigned short* hs     = (unsigned short*)(wsb + 524288);
  unsigned short* a_edge = (unsigned short*)(wsb + 34078720);

  hipMemsetAsync(wsb, 0, 81920, stream);      // yg + cnt
  k_prep<<<320, 256, 0, stream>>>(idx, cnt, Wh, whTg, Wq, Wk, Wv, Wo, wT,
                                  W1, w1Tg);
  k_csr_scan<<<1, 256, 0, stream>>>(cnt, offs, cursor);
  k_csr_fill<<<192, 256, 0, stream>>>(idx, cursor, elist);
  k_gru<<<1024, 256, 0, stream>>>(h0, x, dn, whTg, Wi, bi, bhn, hs, out_hfin);
  for (int half = 0; half < 2; ++half) {
    const int tb0 = half * 8;
    k_attn<<<1024, 256, 0, stream>>>(tb0, hs, idx, wT, bq, bk, bv, a_edge);
    k_head<<<2048, 256, 0, stream>>>(tb0, a_edge, offs, elist, wT, bo, extra,
                                     W1, b1, w1Tg, W2, b2, yg, out_logit);
  }
  k_final<<<1, 256, 0, stream>>>(yg, extra, Wv1, bv1, hg, out_value, out_hg);
}